// Round 3
// baseline (504.841 us; speedup 1.0000x reference)
//
#include <hip/hip_runtime.h>
#include <hip/hip_bf16.h>

// MLA prefill: B=1, T=2048, C=2048, H=16, DN=128, DR=64, DV=128, QKD=192,
// RQ=1536, RKV=512. Inputs f32, output f32.
// Round 9: attn restructured -- barrier-free main loop.
//  * K/V read directly global->reg as MFMA fragments (L2-resident per head;
//    LDS staging + its 2 barriers/iter removed per Common-mistake #7).
//  * 16 q-rows per wave; 2 waves/block split the s-tiles (even/odd) with
//    independent online-softmax state; single LDS combine at block end.
//  * Grid 2048 x 128thr -> 16 waves/CU; 1-D grid, h=id&15 => head->XCD L2
//    affinity; qtile reversed => longest blocks first.
// GEMM keeps the round-8 2-phase double-buffer.

#define T_DIM 2048
#define H_DIM 16
#define SCALE_F 0.07216878364870322f   // 192^-0.5
#define EPS_F 1e-6f
#define NEG_INF (-3.402823466e38f)

typedef __attribute__((ext_vector_type(8))) short short8;
typedef __attribute__((ext_vector_type(4))) float f32x4;
typedef __attribute__((address_space(3))) char lds_char;
typedef const __attribute__((address_space(1))) char glb_char;

__device__ inline void st_out(float* p, float v) { *p = v; }
__device__ inline void st_out(__hip_bfloat16* p, float v) { *p = __float2bfloat16(v); }

// ---------------- f32 -> bf16 cast (optionally zero-padded tail) ------------
__global__ void cast_bf16_kernel(const float* __restrict__ src,
                                 __hip_bfloat16* __restrict__ dst,
                                 int n4_src, int n4_dst) {
    int i = blockIdx.x * 256 + threadIdx.x;
    if (i >= n4_dst) return;
    float4 v = make_float4(0.f, 0.f, 0.f, 0.f);
    if (i < n4_src) v = ((const float4*)src)[i];
    dst[4 * i + 0] = __float2bfloat16(v.x);
    dst[4 * i + 1] = __float2bfloat16(v.y);
    dst[4 * i + 2] = __float2bfloat16(v.z);
    dst[4 * i + 3] = __float2bfloat16(v.w);
}

__global__ void pad_bias_kernel(const float* __restrict__ src, float* __restrict__ dst,
                                int n_src, int n_dst) {
    int i = blockIdx.x * 256 + threadIdx.x;
    if (i < n_dst) dst[i] = (i < n_src) ? src[i] : 0.f;
}

// ---------------- MFMA GEMM: C[M,N] = A[M,K] @ W[N,K]^T + bias[N] -----------
template <typename OT>
__global__ __launch_bounds__(256) void gemm_mfma_kernel(
    const __hip_bfloat16* __restrict__ A, int lda,
    const __hip_bfloat16* __restrict__ W, int ldw,
    const float* __restrict__ bias,
    OT* __restrict__ C, int ldc, int K) {
    __shared__ __hip_bfloat16 As[2][128 * 32];
    __shared__ __hip_bfloat16 Bs[2][128 * 32];
    const int tid = threadIdx.x;
    const int w = tid >> 6, lane = tid & 63, qd = lane >> 4, lx = lane & 15;
    const int rowB = blockIdx.y * 128, colB = blockIdx.x * 128;
    const int wr = (w >> 1) * 64, wc = (w & 1) * 64;

    f32x4 acc[4][4];
#pragma unroll
    for (int i = 0; i < 4; ++i)
#pragma unroll
        for (int j = 0; j < 4; ++j) acc[i][j] = (f32x4)(0.f);

    auto stage = [&](int buf, int k0) {
#pragma unroll
        for (int it = 0; it < 2; ++it) {
            const int g = w * 128 + it * 64 + lane;   // 16B granule index
            const int row = g >> 2, q = g & 3;
            const __hip_bfloat16* ga = A + (size_t)(rowB + row) * lda + k0 + q * 8;
            __builtin_amdgcn_global_load_lds((glb_char*)ga,
                (lds_char*)((char*)&As[buf][0] + (size_t)g * 16), 16, 0, 0);
            const __hip_bfloat16* gb = W + (size_t)(colB + row) * ldw + k0 + q * 8;
            __builtin_amdgcn_global_load_lds((glb_char*)gb,
                (lds_char*)((char*)&Bs[buf][0] + (size_t)g * 16), 16, 0, 0);
        }
    };

    stage(0, 0);
    __syncthreads();          // buf0 ready
    int cur = 0;
    for (int k0 = 0; k0 < K; k0 += 32) {
        if (k0 + 32 < K) stage(cur ^ 1, k0 + 32);   // in flight across compute

        short8 a[4], b[4];
#pragma unroll
        for (int rt = 0; rt < 4; ++rt)
            a[rt] = *(const short8*)&As[cur][(wr + rt * 16 + lx) * 32 + qd * 8];
#pragma unroll
        for (int ct = 0; ct < 4; ++ct)
            b[ct] = *(const short8*)&Bs[cur][(wc + ct * 16 + lx) * 32 + qd * 8];
#pragma unroll
        for (int rt = 0; rt < 4; ++rt)
#pragma unroll
            for (int ct = 0; ct < 4; ++ct)
                acc[rt][ct] = __builtin_amdgcn_mfma_f32_16x16x32_bf16(a[rt], b[ct], acc[rt][ct], 0, 0, 0);
        __syncthreads();
        cur ^= 1;
    }

    // epilogue: C/D layout col=lane&15, row=4*qd+reg
#pragma unroll
    for (int rt = 0; rt < 4; ++rt)
#pragma unroll
        for (int j = 0; j < 4; ++j) {
            const int row = rowB + wr + rt * 16 + 4 * qd + j;
#pragma unroll
            for (int ct = 0; ct < 4; ++ct) {
                const int col = colB + wc + ct * 16 + lx;
                st_out(&C[(size_t)row * ldc + col], acc[rt][ct][j] + bias[col]);
            }
        }
}

// ---------------- RMSNorm: f32 in -> bf16 out -------------------------------
__global__ void rmsnorm_kernel(const float* __restrict__ in, __hip_bfloat16* __restrict__ outp,
                               const float* __restrict__ w,
                               int D, int in_stride, int out_stride) {
    const int row = blockIdx.x;
    const float* p = in + (size_t)row * in_stride;
    __hip_bfloat16* o = outp + (size_t)row * out_stride;
    const int tid = threadIdx.x;  // 256
    float ss = 0.f;
    for (int i = tid; i < D; i += 256) { float v = p[i]; ss += v * v; }
    __shared__ float red[256];
    red[tid] = ss;
    __syncthreads();
    for (int off = 128; off > 0; off >>= 1) {
        if (tid < off) red[tid] += red[tid + off];
        __syncthreads();
    }
    const float scale = rsqrtf(red[0] / (float)D + EPS_F);
    for (int i = tid; i < D; i += 256)
        o[i] = __float2bfloat16(p[i] * scale * w[i]);
}

// ---------------- RoPE on q (in-place on bf16 qb: (T, H*192)) ---------------
__global__ void rope_q_bf_kernel(__hip_bfloat16* __restrict__ qb,
                                 const float* __restrict__ freqs) {
    const int idx = blockIdx.x * 256 + threadIdx.x;
    const int t = idx >> 9;
    const int h = (idx >> 5) & 15;
    const int i = idx & 31;
    const float f = freqs[t * 32 + i];
    const float c = cosf(f), s = sinf(f);
    __hip_bfloat16* p = qb + (size_t)t * 3072 + h * 192 + 128 + 2 * i;
    const float xr = __bfloat162float(p[0]), xi = __bfloat162float(p[1]);
    p[0] = __float2bfloat16(xr * c - xi * s);
    p[1] = __float2bfloat16(xr * s + xi * c);
}

// ---------------- RoPE on k_pe: kvpe f32 (T,640) cols[512:576) -> kpe bf16 --
__global__ void rope_k_bf_kernel(const float* __restrict__ kvpe,
                                 const float* __restrict__ freqs,
                                 __hip_bfloat16* __restrict__ kpe) {
    const int idx = blockIdx.x * 256 + threadIdx.x;  // 65536
    const int t = idx >> 5;
    const int i = idx & 31;
    const float f = freqs[t * 32 + i];
    const float c = cosf(f), s = sinf(f);
    const float* src = kvpe + (size_t)t * 640 + 512 + 2 * i;
    const float xr = src[0], xi = src[1];
    kpe[(size_t)t * 64 + 2 * i]     = __float2bfloat16(xr * c - xi * s);
    kpe[(size_t)t * 64 + 2 * i + 1] = __float2bfloat16(xr * s + xi * c);
}

// ---------------- pack V transposed: kvb_bf (T,H*256) -> vT (H,128,T) -------
__global__ void pack_vT_kernel(const __hip_bfloat16* __restrict__ kvb,
                               __hip_bfloat16* __restrict__ vT) {
    const int t0 = blockIdx.x * 64;
    const int h = blockIdx.y;
    const int tid = threadIdx.x;
    __shared__ __hip_bfloat16 Ls[64][136];
#pragma unroll
    for (int it = 0; it < 4; ++it) {
        int c = tid + 256 * it;
        int i = c >> 4, part = c & 15;
        *(uint4*)&Ls[i][part * 8] =
            *(const uint4*)(kvb + (size_t)(t0 + i) * 4096 + h * 256 + 128 + part * 8);
    }
    __syncthreads();
#pragma unroll
    for (int it = 0; it < 32; ++it) {
        int c = tid + 256 * it;
        int d = c >> 6, i = c & 63;
        vT[((size_t)(h * 128 + d)) * 2048 + t0 + i] = Ls[i][d];
    }
}

// ---------------- MFMA flash attention, barrier-free main loop --------------
// Block = 2 waves x 64 lanes, both owning q rows [r0, r0+16). Wave w handles
// s-tiles t = w, w+2, ... with its own online-softmax state; combined via LDS
// after a single __syncthreads. K/V fragments are loaded straight from global
// (L2-resident: ~1 MB/head; heads h and h+8 pinned to one XCD by the 1-D grid
// decode h = id & 15). P transpose goes through a wave-private LDS slab.
__global__ __launch_bounds__(128) void attn_mfma_kernel(
    const __hip_bfloat16* __restrict__ q,
    const __hip_bfloat16* __restrict__ kv,
    const __hip_bfloat16* __restrict__ kpe,
    const __hip_bfloat16* __restrict__ vT,
    __hip_bfloat16* __restrict__ y) {
    const int id = blockIdx.x;            // 2048 = 128 qtiles * 16 heads
    const int h  = id & 15;               // low bits -> XCD affinity for KV
    const int qt = 127 - (id >> 4);       // longest blocks first
    const int r0 = qt * 16;               // q rows [r0, r0+16)
    const int NT = (qt >> 2) + 1;         // # of 64-wide s-tiles (causal)
    const int tid = threadIdx.x;
    const int w = tid >> 6, lane = tid & 63, qd = lane >> 4, lx = lane & 15;

    __shared__ __hip_bfloat16 Ps[2][16][72];
    __shared__ float Osh[16][132];        // wave1's O for the combine
    __shared__ float msh[16], lsh[16];

    const __hip_bfloat16* kvh = kv + h * 256;
    const __hip_bfloat16* vTh = vT + (size_t)h * 128 * 2048;

    // Q fragments: row r0+lx, k-chunk qd*8 within kc*32
    short8 qf[6];
    {
        const __hip_bfloat16* qrow = q + (size_t)(r0 + lx) * 3072 + h * 192 + qd * 8;
#pragma unroll
        for (int kc = 0; kc < 6; ++kc)
            qf[kc] = *(const short8*)(qrow + kc * 32);
    }

    f32x4 O[8];
#pragma unroll
    for (int i = 0; i < 8; ++i) O[i] = (f32x4)(0.f);
    float mrow[4], lrow[4];
#pragma unroll
    for (int j = 0; j < 4; ++j) { mrow[j] = NEG_INF; lrow[j] = 0.f; }

    for (int t = w; t < NT; t += 2) {
        const int s0 = t * 64;

        // ---- QK^T: B-fragments straight from global (L2) ----
        f32x4 S[4];
#pragma unroll
        for (int nt = 0; nt < 4; ++nt) S[nt] = (f32x4)(0.f);
        __builtin_amdgcn_s_setprio(1);
#pragma unroll
        for (int kc = 0; kc < 6; ++kc) {
            short8 a = qf[kc];
#pragma unroll
            for (int nt = 0; nt < 4; ++nt) {
                const int krow = s0 + nt * 16 + lx;
                const __hip_bfloat16* bp = (kc < 4)
                    ? kvh + (size_t)krow * 4096 + kc * 32 + qd * 8
                    : kpe + (size_t)krow * 64 + (kc - 4) * 32 + qd * 8;
                short8 b = *(const short8*)bp;
                S[nt] = __builtin_amdgcn_mfma_f32_16x16x32_bf16(a, b, S[nt], 0, 0, 0);
            }
        }
        __builtin_amdgcn_s_setprio(0);

        // ---- mask + scale ----
        float sv[4][4];
#pragma unroll
        for (int nt = 0; nt < 4; ++nt) {
            const int col = s0 + nt * 16 + lx;
#pragma unroll
            for (int j = 0; j < 4; ++j) {
                const int row = r0 + 4 * qd + j;
                float v = S[nt][j] * SCALE_F;
                sv[nt][j] = (col > row) ? NEG_INF : v;
            }
        }

        // ---- online softmax over this wave's tiles ----
        float mn[4], al[4], rs[4];
#pragma unroll
        for (int j = 0; j < 4; ++j) {
            float rm = fmaxf(fmaxf(sv[0][j], sv[1][j]), fmaxf(sv[2][j], sv[3][j]));
#pragma unroll
            for (int msk = 1; msk < 16; msk <<= 1)
                rm = fmaxf(rm, __shfl_xor(rm, msk));
            mn[j] = fmaxf(mrow[j], rm);
            al[j] = __expf(mrow[j] - mn[j]);
            rs[j] = 0.f;
        }
#pragma unroll
        for (int nt = 0; nt < 4; ++nt)
#pragma unroll
            for (int j = 0; j < 4; ++j) {
                float p = __expf(sv[nt][j] - mn[j]);
                rs[j] += p;
                Ps[w][4 * qd + j][nt * 16 + lx] = __float2bfloat16(p);
            }
#pragma unroll
        for (int j = 0; j < 4; ++j) {
#pragma unroll
            for (int msk = 1; msk < 16; msk <<= 1)
                rs[j] += __shfl_xor(rs[j], msk);
            lrow[j] = lrow[j] * al[j] + rs[j];
            mrow[j] = mn[j];
        }
#pragma unroll
        for (int nt = 0; nt < 8; ++nt)
#pragma unroll
            for (int j = 0; j < 4; ++j) O[nt][j] *= al[j];

        // wave-private Ps write -> read: only lgkmcnt needed, no barrier
        asm volatile("s_waitcnt lgkmcnt(0)" ::: "memory");

        // ---- PV: V^T fragments straight from global (L2) ----
        __builtin_amdgcn_s_setprio(1);
#pragma unroll
        for (int kc2 = 0; kc2 < 2; ++kc2) {
            short8 pa = *(const short8*)&Ps[w][lx][kc2 * 32 + qd * 8];
#pragma unroll
            for (int nt = 0; nt < 8; ++nt) {
                short8 vb = *(const short8*)(vTh + (size_t)(nt * 16 + lx) * 2048
                                             + s0 + kc2 * 32 + qd * 8);
                O[nt] = __builtin_amdgcn_mfma_f32_16x16x32_bf16(pa, vb, O[nt], 0, 0, 0);
            }
        }
        __builtin_amdgcn_s_setprio(0);
    }

    // ---- cross-wave combine (single barrier per block) ----
    if (w == 1) {
#pragma unroll
        for (int j = 0; j < 4; ++j) {
            const int r = 4 * qd + j;
            if (lx == 0) { msh[r] = mrow[j]; lsh[r] = lrow[j]; }
#pragma unroll
            for (int nt = 0; nt < 8; ++nt)
                Osh[r][nt * 16 + lx] = O[nt][j];
        }
    }
    __syncthreads();
    if (w == 0) {
#pragma unroll
        for (int j = 0; j < 4; ++j) {
            const int r = 4 * qd + j;
            const float m1 = msh[r], l1 = lsh[r];
            const float M  = fmaxf(mrow[j], m1);
            const float a0 = __expf(mrow[j] - M);
            const float a1 = __expf(m1 - M);       // 0 when wave1 idle (m1=-inf)
            const float inv = 1.f / (lrow[j] * a0 + l1 * a1);
            const int t = r0 + r;
            __hip_bfloat16* yr = y + (size_t)t * 2048 + h * 128 + lx;
#pragma unroll
            for (int nt = 0; nt < 8; ++nt)
                yr[nt * 16] = __float2bfloat16(
                    (O[nt][j] * a0 + Osh[r][nt * 16 + lx] * a1) * inv);
        }
    }
}

extern "C" void kernel_launch(void* const* d_in, const int* in_sizes, int n_in,
                              void* d_out, int out_size, void* d_ws, size_t ws_size,
                              hipStream_t stream) {
    const float* x         = (const float*)d_in[0];
    const float* freqs     = (const float*)d_in[1];
    const float* wq_a      = (const float*)d_in[2];
    const float* bq_a      = (const float*)d_in[3];
    const float* q_norm_w  = (const float*)d_in[4];
    const float* wq_b      = (const float*)d_in[5];
    const float* bq_b      = (const float*)d_in[6];
    const float* wkv_a     = (const float*)d_in[7];
    const float* bkv_a     = (const float*)d_in[8];
    const float* kv_norm_w = (const float*)d_in[9];
    const float* wkv_b     = (const float*)d_in[10];
    const float* bkv_b     = (const float*)d_in[11];
    const float* wo        = (const float*)d_in[12];
    const float* bo        = (const float*)d_in[13];
    float* out = (float*)d_out;

    // Workspace layout, ~76.3 MB total.
    char* p = (char*)d_ws;
    float* q_lat = (float*)p;                        p += (size_t)2048 * 1536 * 4;  // later hosts yb_bf
    float* kvpe  = (float*)p;                        p += (size_t)2048 * 640 * 4;
    __hip_bfloat16* x_bf      = (__hip_bfloat16*)p;  p += (size_t)2048 * 2048 * 2;  // later hosts vT
    __hip_bfloat16* q_lat_bf  = (__hip_bfloat16*)p;  p += (size_t)2048 * 1536 * 2;
    __hip_bfloat16* qb_bf     = (__hip_bfloat16*)p;  p += (size_t)2048 * 3072 * 2;
    __hip_bfloat16* kv_lat_bf = (__hip_bfloat16*)p;  p += (size_t)2048 * 512 * 2;
    __hip_bfloat16* kvb_bf    = (__hip_bfloat16*)p;  p += (size_t)2048 * 4096 * 2;
    __hip_bfloat16* kpe_bf    = (__hip_bfloat16*)p;  p += (size_t)2048 * 64 * 2;
    __hip_bfloat16* WA        = (__hip_bfloat16*)p;  p += (size_t)3072 * 1536 * 2;  // weight arena (max 9.44 MB)
    __hip_bfloat16* WB        = (__hip_bfloat16*)p;  p += (size_t)640 * 2048 * 2;   // padded wkv_a
    float* bkv_pad = (float*)p;                      p += (size_t)640 * 4;
    __hip_bfloat16* vT    = x_bf;                    // alias: x_bf dead after GEMM 2
    __hip_bfloat16* yb_bf = (__hip_bfloat16*)q_lat;  // alias: q_lat dead after rmsnorm

    // ---- casts & pads ----
    cast_bf16_kernel<<<4096, 256, 0, stream>>>(x, x_bf, 1048576, 1048576);
    cast_bf16_kernel<<<3072, 256, 0, stream>>>(wq_a, WA, 786432, 786432);
    // GEMM 1: q_lat = x @ wq_a^T + bq_a  (f32 out)
    gemm_mfma_kernel<float><<<dim3(12, 16), 256, 0, stream>>>(x_bf, 2048, WA, 2048, bq_a, q_lat, 1536, 2048);
    cast_bf16_kernel<<<1280, 256, 0, stream>>>(wkv_a, WB, 294912, 327680);
    pad_bias_kernel<<<3, 256, 0, stream>>>(bkv_a, bkv_pad, 576, 640);
    // GEMM 2: kvpe = x @ wkv_a^T + bkv_a  (f32 out, N padded to 640)
    gemm_mfma_kernel<float><<<dim3(5, 16), 256, 0, stream>>>(x_bf, 2048, WB, 2048, bkv_pad, kvpe, 640, 2048);
    // rmsnorm q -> bf16
    rmsnorm_kernel<<<2048, 256, 0, stream>>>(q_lat, q_lat_bf, q_norm_w, 1536, 1536, 1536);
    cast_bf16_kernel<<<4608, 256, 0, stream>>>(wq_b, WA, 1179648, 1179648);
    // GEMM 3: qb_bf = q_lat_bf @ wq_b^T + bq_b
    gemm_mfma_kernel<__hip_bfloat16><<<dim3(24, 16), 256, 0, stream>>>(q_lat_bf, 1536, WA, 1536, bq_b, qb_bf, 3072, 1536);
    rope_q_bf_kernel<<<4096, 256, 0, stream>>>(qb_bf, freqs);
    rope_k_bf_kernel<<<256, 256, 0, stream>>>(kvpe, freqs, kpe_bf);
    rmsnorm_kernel<<<2048, 256, 0, stream>>>(kvpe, kv_lat_bf, kv_norm_w, 512, 640, 512);
    cast_bf16_kernel<<<2048, 256, 0, stream>>>(wkv_b, WA, 524288, 524288);
    // GEMM 4: kvb_bf = kv_lat_bf @ wkv_b^T + bkv_b
    gemm_mfma_kernel<__hip_bfloat16><<<dim3(32, 16), 256, 0, stream>>>(kv_lat_bf, 512, WA, 512, bkv_b, kvb_bf, 4096, 512);
    pack_vT_kernel<<<dim3(32, 16), 256, 0, stream>>>(kvb_bf, vT);
    attn_mfma_kernel<<<2048, 128, 0, stream>>>(qb_bf, kvb_bf, kpe_bf, vT, yb_bf);
    cast_bf16_kernel<<<4096, 256, 0, stream>>>(wo, WA, 1048576, 1048576);
    // GEMM 5: out = yb_bf @ wo^T + bo  (f32 out)
    gemm_mfma_kernel<float><<<dim3(16, 16), 256, 0, stream>>>(yb_bf, 2048, WA, 2048, bo, out, 2048, 2048);
}

// Round 4
// 467.206 us; speedup vs baseline: 1.0806x; 1.0806x over previous
//
#include <hip/hip_runtime.h>
#include <hip/hip_bf16.h>

// MLA prefill: B=1, T=2048, C=2048, H=16, DN=128, DR=64, DV=128, QKD=192,
// RQ=1536, RKV=512. Inputs f32, output f32.
// Round 10: flash-decoding split-s attention.
//  * Round-2 tile internals restored verbatim (LDS staging + named-reg T14
//    prefetch + setprio) -- round 9's direct-global fragments were an L2
//    latency trap (64 lines/wave-load), reverted.
//  * Each (qtile, head) split into chunks of <=8 s-tiles; independent online
//    softmax per chunk; normalized bf16 partial O + (m,l) to workspace; small
//    combine kernel merges <=4 chunks. Critical path 32 -> 8 iters and CUs
//    stay packed (no triangular occupancy decay).
//  * Partial arena (21.6 MB) aliases the dead-during-attn pool
//    (kvpe/q_lat_bf/kv_lat_bf/WA/WB, reordered contiguous, 25.7 MB).
// GEMM keeps the 2-phase double-buffer.

#define T_DIM 2048
#define H_DIM 16
#define SCALE_F 0.07216878364870322f   // 192^-0.5
#define EPS_F 1e-6f
#define NEG_INF (-3.402823466e38f)

typedef __attribute__((ext_vector_type(8))) short short8;
typedef __attribute__((ext_vector_type(4))) float f32x4;
typedef __attribute__((address_space(3))) char lds_char;
typedef const __attribute__((address_space(1))) char glb_char;

__device__ inline void st_out(float* p, float v) { *p = v; }
__device__ inline void st_out(__hip_bfloat16* p, float v) { *p = __float2bfloat16(v); }

// ---------------- f32 -> bf16 cast (optionally zero-padded tail) ------------
__global__ void cast_bf16_kernel(const float* __restrict__ src,
                                 __hip_bfloat16* __restrict__ dst,
                                 int n4_src, int n4_dst) {
    int i = blockIdx.x * 256 + threadIdx.x;
    if (i >= n4_dst) return;
    float4 v = make_float4(0.f, 0.f, 0.f, 0.f);
    if (i < n4_src) v = ((const float4*)src)[i];
    dst[4 * i + 0] = __float2bfloat16(v.x);
    dst[4 * i + 1] = __float2bfloat16(v.y);
    dst[4 * i + 2] = __float2bfloat16(v.z);
    dst[4 * i + 3] = __float2bfloat16(v.w);
}

__global__ void pad_bias_kernel(const float* __restrict__ src, float* __restrict__ dst,
                                int n_src, int n_dst) {
    int i = blockIdx.x * 256 + threadIdx.x;
    if (i < n_dst) dst[i] = (i < n_src) ? src[i] : 0.f;
}

// ---------------- MFMA GEMM: C[M,N] = A[M,K] @ W[N,K]^T + bias[N] -----------
template <typename OT>
__global__ __launch_bounds__(256) void gemm_mfma_kernel(
    const __hip_bfloat16* __restrict__ A, int lda,
    const __hip_bfloat16* __restrict__ W, int ldw,
    const float* __restrict__ bias,
    OT* __restrict__ C, int ldc, int K) {
    __shared__ __hip_bfloat16 As[2][128 * 32];
    __shared__ __hip_bfloat16 Bs[2][128 * 32];
    const int tid = threadIdx.x;
    const int w = tid >> 6, lane = tid & 63, qd = lane >> 4, lx = lane & 15;
    const int rowB = blockIdx.y * 128, colB = blockIdx.x * 128;
    const int wr = (w >> 1) * 64, wc = (w & 1) * 64;

    f32x4 acc[4][4];
#pragma unroll
    for (int i = 0; i < 4; ++i)
#pragma unroll
        for (int j = 0; j < 4; ++j) acc[i][j] = (f32x4)(0.f);

    auto stage = [&](int buf, int k0) {
#pragma unroll
        for (int it = 0; it < 2; ++it) {
            const int g = w * 128 + it * 64 + lane;   // 16B granule index
            const int row = g >> 2, q = g & 3;
            const __hip_bfloat16* ga = A + (size_t)(rowB + row) * lda + k0 + q * 8;
            __builtin_amdgcn_global_load_lds((glb_char*)ga,
                (lds_char*)((char*)&As[buf][0] + (size_t)g * 16), 16, 0, 0);
            const __hip_bfloat16* gb = W + (size_t)(colB + row) * ldw + k0 + q * 8;
            __builtin_amdgcn_global_load_lds((glb_char*)gb,
                (lds_char*)((char*)&Bs[buf][0] + (size_t)g * 16), 16, 0, 0);
        }
    };

    stage(0, 0);
    __syncthreads();          // buf0 ready
    int cur = 0;
    for (int k0 = 0; k0 < K; k0 += 32) {
        if (k0 + 32 < K) stage(cur ^ 1, k0 + 32);   // in flight across compute

        short8 a[4], b[4];
#pragma unroll
        for (int rt = 0; rt < 4; ++rt)
            a[rt] = *(const short8*)&As[cur][(wr + rt * 16 + lx) * 32 + qd * 8];
#pragma unroll
        for (int ct = 0; ct < 4; ++ct)
            b[ct] = *(const short8*)&Bs[cur][(wc + ct * 16 + lx) * 32 + qd * 8];
#pragma unroll
        for (int rt = 0; rt < 4; ++rt)
#pragma unroll
            for (int ct = 0; ct < 4; ++ct)
                acc[rt][ct] = __builtin_amdgcn_mfma_f32_16x16x32_bf16(a[rt], b[ct], acc[rt][ct], 0, 0, 0);
        __syncthreads();
        cur ^= 1;
    }

    // epilogue: C/D layout col=lane&15, row=4*qd+reg
#pragma unroll
    for (int rt = 0; rt < 4; ++rt)
#pragma unroll
        for (int j = 0; j < 4; ++j) {
            const int row = rowB + wr + rt * 16 + 4 * qd + j;
#pragma unroll
            for (int ct = 0; ct < 4; ++ct) {
                const int col = colB + wc + ct * 16 + lx;
                st_out(&C[(size_t)row * ldc + col], acc[rt][ct][j] + bias[col]);
            }
        }
}

// ---------------- RMSNorm: f32 in -> bf16 out -------------------------------
__global__ void rmsnorm_kernel(const float* __restrict__ in, __hip_bfloat16* __restrict__ outp,
                               const float* __restrict__ w,
                               int D, int in_stride, int out_stride) {
    const int row = blockIdx.x;
    const float* p = in + (size_t)row * in_stride;
    __hip_bfloat16* o = outp + (size_t)row * out_stride;
    const int tid = threadIdx.x;  // 256
    float ss = 0.f;
    for (int i = tid; i < D; i += 256) { float v = p[i]; ss += v * v; }
    __shared__ float red[256];
    red[tid] = ss;
    __syncthreads();
    for (int off = 128; off > 0; off >>= 1) {
        if (tid < off) red[tid] += red[tid + off];
        __syncthreads();
    }
    const float scale = rsqrtf(red[0] / (float)D + EPS_F);
    for (int i = tid; i < D; i += 256)
        o[i] = __float2bfloat16(p[i] * scale * w[i]);
}

// ---------------- RoPE on q (in-place on bf16 qb: (T, H*192)) ---------------
__global__ void rope_q_bf_kernel(__hip_bfloat16* __restrict__ qb,
                                 const float* __restrict__ freqs) {
    const int idx = blockIdx.x * 256 + threadIdx.x;
    const int t = idx >> 9;
    const int h = (idx >> 5) & 15;
    const int i = idx & 31;
    const float f = freqs[t * 32 + i];
    const float c = cosf(f), s = sinf(f);
    __hip_bfloat16* p = qb + (size_t)t * 3072 + h * 192 + 128 + 2 * i;
    const float xr = __bfloat162float(p[0]), xi = __bfloat162float(p[1]);
    p[0] = __float2bfloat16(xr * c - xi * s);
    p[1] = __float2bfloat16(xr * s + xi * c);
}

// ---------------- RoPE on k_pe: kvpe f32 (T,640) cols[512:576) -> kpe bf16 --
__global__ void rope_k_bf_kernel(const float* __restrict__ kvpe,
                                 const float* __restrict__ freqs,
                                 __hip_bfloat16* __restrict__ kpe) {
    const int idx = blockIdx.x * 256 + threadIdx.x;  // 65536
    const int t = idx >> 5;
    const int i = idx & 31;
    const float f = freqs[t * 32 + i];
    const float c = cosf(f), s = sinf(f);
    const float* src = kvpe + (size_t)t * 640 + 512 + 2 * i;
    const float xr = src[0], xi = src[1];
    kpe[(size_t)t * 64 + 2 * i]     = __float2bfloat16(xr * c - xi * s);
    kpe[(size_t)t * 64 + 2 * i + 1] = __float2bfloat16(xr * s + xi * c);
}

// ---------------- pack V transposed: kvb_bf (T,H*256) -> vT (H,128,T) -------
__global__ void pack_vT_kernel(const __hip_bfloat16* __restrict__ kvb,
                               __hip_bfloat16* __restrict__ vT) {
    const int t0 = blockIdx.x * 64;
    const int h = blockIdx.y;
    const int tid = threadIdx.x;
    __shared__ __hip_bfloat16 Ls[64][136];
#pragma unroll
    for (int it = 0; it < 4; ++it) {
        int c = tid + 256 * it;
        int i = c >> 4, part = c & 15;
        *(uint4*)&Ls[i][part * 8] =
            *(const uint4*)(kvb + (size_t)(t0 + i) * 4096 + h * 256 + 128 + part * 8);
    }
    __syncthreads();
#pragma unroll
    for (int it = 0; it < 32; ++it) {
        int c = tid + 256 * it;
        int d = c >> 6, i = c & 63;
        vT[((size_t)(h * 128 + d)) * 2048 + t0 + i] = Ls[i][d];
    }
}

// ---------------- MFMA flash attention, split-s partial kernel --------------
// Round-2 tile internals verbatim; each block processes s-tile chunk
// [c*8, min(c*8+8, qt+1)) of one (qtile, head), writes normalized bf16
// partial O + per-row (m, l) to the workspace arena.
// Slot index: base(qt) = 4a(a+1) + b(a+1) with a=qt>>3, b=qt&7 (prefix sum of
// ceil((q+1)/8)); slot = h*80 + base + c. 1280 active slots.
__global__ __launch_bounds__(256) void attn_part_kernel(
    const __hip_bfloat16* __restrict__ q,
    const __hip_bfloat16* __restrict__ kv,
    const __hip_bfloat16* __restrict__ kpe,
    const __hip_bfloat16* __restrict__ vT,
    __hip_bfloat16* __restrict__ Opart,
    float2* __restrict__ mlpart) {
    const int xb = blockIdx.x;            // 0..127
    const int qt = 31 - (xb >> 2);        // longest qtiles first
    const int c  = xb & 3;
    const int nchunks = (qt + 8) >> 3;    // ceil((qt+1)/8)
    if (c >= nchunks) return;
    const int h = blockIdx.y;
    const int q0 = qt * 64;
    const int NT = qt + 1;
    const int t0 = c * 8;
    const int tend = min(t0 + 8, NT);
    const int a_ = qt >> 3;
    const int slot = h * 80 + 4 * a_ * (a_ + 1) + (qt & 7) * (a_ + 1) + c;

    const int tid = threadIdx.x;
    const int w = tid >> 6, lane = tid & 63, qd = lane >> 4, lx = lane & 15;

    __shared__ __hip_bfloat16 Ks[64][200];
    __shared__ __hip_bfloat16 Vs[128][72];
    __shared__ __hip_bfloat16 Ps[4][16][72];

    short8 qf[6];
    {
        const __hip_bfloat16* qrow =
            q + (size_t)(q0 + 16 * w + lx) * 3072 + h * 192 + qd * 8;
#pragma unroll
        for (int kc = 0; kc < 6; ++kc)
            qf[kc] = *(const short8*)(qrow + kc * 32);
    }

    f32x4 O[8];
#pragma unroll
    for (int i = 0; i < 8; ++i) O[i] = (f32x4)(0.f);
    float mrow[4], lrow[4];
#pragma unroll
    for (int j = 0; j < 4; ++j) { mrow[j] = NEG_INF; lrow[j] = 0.f; }

    // ---- prefetch state: 10 NAMED uint4 (40 VGPRs), never indexed ----
    uint4 k0r, k1r, k2r, k3r, pe0r, pe1r, v0r, v1r, v2r, v3r;
    const __hip_bfloat16* kvh = kv + h * 256;
    const __hip_bfloat16* vTh = vT + (size_t)h * 128 * 2048;

#define PREFETCH(S0)                                                               \
    do {                                                                           \
        const size_t kk_ = (size_t)(S0) + (tid >> 4);                              \
        const int kp_ = (tid & 15) * 8;                                            \
        k0r = *(const uint4*)(kvh + (kk_ +  0) * 4096 + kp_);                      \
        k1r = *(const uint4*)(kvh + (kk_ + 16) * 4096 + kp_);                      \
        k2r = *(const uint4*)(kvh + (kk_ + 32) * 4096 + kp_);                      \
        k3r = *(const uint4*)(kvh + (kk_ + 48) * 4096 + kp_);                      \
        const size_t pk_ = (size_t)(S0) + (tid >> 3);                              \
        const int pp_ = (tid & 7) * 8;                                             \
        pe0r = *(const uint4*)(kpe + (pk_ +  0) * 64 + pp_);                       \
        pe1r = *(const uint4*)(kpe + (pk_ + 32) * 64 + pp_);                       \
        const __hip_bfloat16* vp_ = vTh + ((size_t)(tid >> 3)) * 2048 + (S0) + pp_;\
        v0r = *(const uint4*)(vp_ + 0 * 65536);                                    \
        v1r = *(const uint4*)(vp_ + 1 * 65536);                                    \
        v2r = *(const uint4*)(vp_ + 2 * 65536);                                    \
        v3r = *(const uint4*)(vp_ + 3 * 65536);                                    \
    } while (0)

    PREFETCH(t0 * 64);

    for (int t = t0; t < tend; ++t) {
        const int s0 = t * 64;
        __syncthreads();   // all waves done reading LDS of previous tile
        {
            const int kr_ = tid >> 4, kp_ = (tid & 15) * 8;
            *(uint4*)&Ks[kr_ +  0][kp_] = k0r;
            *(uint4*)&Ks[kr_ + 16][kp_] = k1r;
            *(uint4*)&Ks[kr_ + 32][kp_] = k2r;
            *(uint4*)&Ks[kr_ + 48][kp_] = k3r;
            const int pr_ = tid >> 3, pp_ = (tid & 7) * 8;
            *(uint4*)&Ks[pr_ +  0][128 + pp_] = pe0r;
            *(uint4*)&Ks[pr_ + 32][128 + pp_] = pe1r;
            *(uint4*)&Vs[pr_ +  0][pp_] = v0r;
            *(uint4*)&Vs[pr_ + 32][pp_] = v1r;
            *(uint4*)&Vs[pr_ + 64][pp_] = v2r;
            *(uint4*)&Vs[pr_ + 96][pp_] = v3r;
        }
        __syncthreads();   // tile visible to all waves

        if (t + 1 < tend) PREFETCH((t + 1) * 64);

        f32x4 S[4];
#pragma unroll
        for (int nt = 0; nt < 4; ++nt) S[nt] = (f32x4)(0.f);
        __builtin_amdgcn_s_setprio(1);
#pragma unroll
        for (int kc = 0; kc < 6; ++kc) {
            short8 a = qf[kc];
#pragma unroll
            for (int nt = 0; nt < 4; ++nt) {
                short8 b = *(const short8*)&Ks[nt * 16 + lx][kc * 32 + qd * 8];
                S[nt] = __builtin_amdgcn_mfma_f32_16x16x32_bf16(a, b, S[nt], 0, 0, 0);
            }
        }
        __builtin_amdgcn_s_setprio(0);

        float sv[4][4];
#pragma unroll
        for (int nt = 0; nt < 4; ++nt) {
            int col = s0 + nt * 16 + lx;
#pragma unroll
            for (int j = 0; j < 4; ++j) {
                int row = q0 + 16 * w + 4 * qd + j;
                float v = S[nt][j] * SCALE_F;
                sv[nt][j] = (col > row) ? NEG_INF : v;
            }
        }

        float mn[4], al[4], rs[4];
#pragma unroll
        for (int j = 0; j < 4; ++j) {
            float rm = fmaxf(fmaxf(sv[0][j], sv[1][j]), fmaxf(sv[2][j], sv[3][j]));
#pragma unroll
            for (int msk = 1; msk < 16; msk <<= 1)
                rm = fmaxf(rm, __shfl_xor(rm, msk));
            mn[j] = fmaxf(mrow[j], rm);
            al[j] = __expf(mrow[j] - mn[j]);
            rs[j] = 0.f;
        }
#pragma unroll
        for (int nt = 0; nt < 4; ++nt)
#pragma unroll
            for (int j = 0; j < 4; ++j) {
                float p = __expf(sv[nt][j] - mn[j]);
                rs[j] += p;
                Ps[w][4 * qd + j][nt * 16 + lx] = __float2bfloat16(p);
            }
#pragma unroll
        for (int j = 0; j < 4; ++j) {
#pragma unroll
            for (int msk = 1; msk < 16; msk <<= 1)
                rs[j] += __shfl_xor(rs[j], msk);
            lrow[j] = lrow[j] * al[j] + rs[j];
            mrow[j] = mn[j];
        }
#pragma unroll
        for (int nt = 0; nt < 8; ++nt)
#pragma unroll
            for (int j = 0; j < 4; ++j) O[nt][j] *= al[j];

        asm volatile("s_waitcnt lgkmcnt(0)" ::: "memory");

        __builtin_amdgcn_s_setprio(1);
#pragma unroll
        for (int kc2 = 0; kc2 < 2; ++kc2) {
            short8 pa = *(const short8*)&Ps[w][lx][kc2 * 32 + qd * 8];
#pragma unroll
            for (int nt = 0; nt < 8; ++nt) {
                short8 vb = *(const short8*)&Vs[nt * 16 + lx][kc2 * 32 + qd * 8];
                O[nt] = __builtin_amdgcn_mfma_f32_16x16x32_bf16(pa, vb, O[nt], 0, 0, 0);
            }
        }
        __builtin_amdgcn_s_setprio(0);
    }
#undef PREFETCH

    // ---- write normalized bf16 partial + (m, l) per row ----
#pragma unroll
    for (int j = 0; j < 4; ++j) {
        const int r = 16 * w + 4 * qd + j;             // 0..63
        const float inv = 1.f / lrow[j];               // l > 0 always (diag)
        if (lx == 0) mlpart[(size_t)slot * 64 + r] = make_float2(mrow[j], lrow[j]);
        __hip_bfloat16* op = Opart + ((size_t)slot * 64 + r) * 128 + lx;
#pragma unroll
        for (int nt = 0; nt < 8; ++nt)
            op[nt * 16] = __float2bfloat16(O[nt][j] * inv);
    }
}

// ---------------- combine partials -> y (bf16) ------------------------------
// grid (32, 16), 256 thr. Thread: row = tid>>2 (0..63), 32 cols (tid&3)*32..
__global__ __launch_bounds__(256) void attn_combine_kernel(
    const __hip_bfloat16* __restrict__ Opart,
    const float2* __restrict__ mlpart,
    __hip_bfloat16* __restrict__ y) {
    const int qt = blockIdx.x;
    const int h  = blockIdx.y;
    const int tid = threadIdx.x;
    const int row = tid >> 2;
    const int c0  = (tid & 3) * 32;
    const int nchunks = (qt + 8) >> 3;
    const int a_ = qt >> 3;
    const int slot0 = h * 80 + 4 * a_ * (a_ + 1) + (qt & 7) * (a_ + 1);

    float2 ml0 = mlpart[(size_t)(slot0 + 0) * 64 + row];
    float2 ml1 = (nchunks > 1) ? mlpart[(size_t)(slot0 + 1) * 64 + row] : make_float2(NEG_INF, 0.f);
    float2 ml2 = (nchunks > 2) ? mlpart[(size_t)(slot0 + 2) * 64 + row] : make_float2(NEG_INF, 0.f);
    float2 ml3 = (nchunks > 3) ? mlpart[(size_t)(slot0 + 3) * 64 + row] : make_float2(NEG_INF, 0.f);
    const float M = fmaxf(fmaxf(ml0.x, ml1.x), fmaxf(ml2.x, ml3.x));
    const float w0 = ml0.y * __expf(ml0.x - M);
    const float w1 = (nchunks > 1) ? ml1.y * __expf(ml1.x - M) : 0.f;
    const float w2 = (nchunks > 2) ? ml2.y * __expf(ml2.x - M) : 0.f;
    const float w3 = (nchunks > 3) ? ml3.y * __expf(ml3.x - M) : 0.f;
    const float inv = 1.f / (w0 + w1 + w2 + w3);

    const __hip_bfloat16* base = Opart + ((size_t)slot0 * 64 + row) * 128 + c0;
    __hip_bfloat16* yr = y + (size_t)(qt * 64 + row) * 2048 + h * 128 + c0;
#pragma unroll
    for (int k = 0; k < 4; ++k) {
        float acc[8];
        short8 o0 = *(const short8*)(base + k * 8);
#pragma unroll
        for (int e = 0; e < 8; ++e)
            acc[e] = w0 * __bfloat162float(((const __hip_bfloat16*)&o0)[e]);
        if (nchunks > 1) {
            short8 o1 = *(const short8*)(base + 64 * 128 + k * 8);
#pragma unroll
            for (int e = 0; e < 8; ++e)
                acc[e] += w1 * __bfloat162float(((const __hip_bfloat16*)&o1)[e]);
        }
        if (nchunks > 2) {
            short8 o2 = *(const short8*)(base + 2 * 64 * 128 + k * 8);
#pragma unroll
            for (int e = 0; e < 8; ++e)
                acc[e] += w2 * __bfloat162float(((const __hip_bfloat16*)&o2)[e]);
        }
        if (nchunks > 3) {
            short8 o3 = *(const short8*)(base + 3 * 64 * 128 + k * 8);
#pragma unroll
            for (int e = 0; e < 8; ++e)
                acc[e] += w3 * __bfloat162float(((const __hip_bfloat16*)&o3)[e]);
        }
#pragma unroll
        for (int e = 0; e < 8; ++e)
            yr[k * 8 + e] = __float2bfloat16(acc[e] * inv);
    }
}

extern "C" void kernel_launch(void* const* d_in, const int* in_sizes, int n_in,
                              void* d_out, int out_size, void* d_ws, size_t ws_size,
                              hipStream_t stream) {
    const float* x         = (const float*)d_in[0];
    const float* freqs     = (const float*)d_in[1];
    const float* wq_a      = (const float*)d_in[2];
    const float* bq_a      = (const float*)d_in[3];
    const float* q_norm_w  = (const float*)d_in[4];
    const float* wq_b      = (const float*)d_in[5];
    const float* bq_b      = (const float*)d_in[6];
    const float* wkv_a     = (const float*)d_in[7];
    const float* bkv_a     = (const float*)d_in[8];
    const float* kv_norm_w = (const float*)d_in[9];
    const float* wkv_b     = (const float*)d_in[10];
    const float* bkv_b     = (const float*)d_in[11];
    const float* wo        = (const float*)d_in[12];
    const float* bo        = (const float*)d_in[13];
    float* out = (float*)d_out;

    // Workspace layout, ~76.3 MB total. Buffers dead during attention are
    // grouped into a contiguous pool that hosts the split-s partial arena.
    char* p = (char*)d_ws;
    float* q_lat = (float*)p;                        p += (size_t)2048 * 1536 * 4;  // later hosts yb_bf
    __hip_bfloat16* qb_bf     = (__hip_bfloat16*)p;  p += (size_t)2048 * 3072 * 2;
    __hip_bfloat16* kvb_bf    = (__hip_bfloat16*)p;  p += (size_t)2048 * 4096 * 2;
    __hip_bfloat16* kpe_bf    = (__hip_bfloat16*)p;  p += (size_t)2048 * 64 * 2;
    __hip_bfloat16* x_bf      = (__hip_bfloat16*)p;  p += (size_t)2048 * 2048 * 2;  // later hosts vT
    char* pool = p;                                  // ---- dead-during-attn pool (25.7 MB) ----
    float* kvpe  = (float*)p;                        p += (size_t)2048 * 640 * 4;
    __hip_bfloat16* q_lat_bf  = (__hip_bfloat16*)p;  p += (size_t)2048 * 1536 * 2;
    __hip_bfloat16* kv_lat_bf = (__hip_bfloat16*)p;  p += (size_t)2048 * 512 * 2;
    __hip_bfloat16* WA        = (__hip_bfloat16*)p;  p += (size_t)3072 * 1536 * 2;  // weight arena (max 9.44 MB)
    __hip_bfloat16* WB        = (__hip_bfloat16*)p;  p += (size_t)640 * 2048 * 2;   // padded wkv_a
    float* bkv_pad = (float*)p;                      p += (size_t)640 * 4;
    __hip_bfloat16* vT    = x_bf;                    // alias: x_bf dead after GEMM 2
    __hip_bfloat16* yb_bf = (__hip_bfloat16*)q_lat;  // alias: q_lat dead after rmsnorm
    // partial arena aliases the pool: 1280 slots x 64 rows x 128 bf16 (21.0 MB)
    // + 1280 x 64 float2 (0.66 MB) = 21.6 MB <= 25.7 MB.
    __hip_bfloat16* Opart = (__hip_bfloat16*)pool;
    float2* mlpart = (float2*)(pool + (size_t)1280 * 64 * 128 * 2);

    // ---- casts & pads ----
    cast_bf16_kernel<<<4096, 256, 0, stream>>>(x, x_bf, 1048576, 1048576);
    cast_bf16_kernel<<<3072, 256, 0, stream>>>(wq_a, WA, 786432, 786432);
    // GEMM 1: q_lat = x @ wq_a^T + bq_a  (f32 out)
    gemm_mfma_kernel<float><<<dim3(12, 16), 256, 0, stream>>>(x_bf, 2048, WA, 2048, bq_a, q_lat, 1536, 2048);
    cast_bf16_kernel<<<1280, 256, 0, stream>>>(wkv_a, WB, 294912, 327680);
    pad_bias_kernel<<<3, 256, 0, stream>>>(bkv_a, bkv_pad, 576, 640);
    // GEMM 2: kvpe = x @ wkv_a^T + bkv_a  (f32 out, N padded to 640)
    gemm_mfma_kernel<float><<<dim3(5, 16), 256, 0, stream>>>(x_bf, 2048, WB, 2048, bkv_pad, kvpe, 640, 2048);
    // rmsnorm q -> bf16
    rmsnorm_kernel<<<2048, 256, 0, stream>>>(q_lat, q_lat_bf, q_norm_w, 1536, 1536, 1536);
    cast_bf16_kernel<<<4608, 256, 0, stream>>>(wq_b, WA, 1179648, 1179648);
    // GEMM 3: qb_bf = q_lat_bf @ wq_b^T + bq_b
    gemm_mfma_kernel<__hip_bfloat16><<<dim3(24, 16), 256, 0, stream>>>(q_lat_bf, 1536, WA, 1536, bq_b, qb_bf, 3072, 1536);
    rope_q_bf_kernel<<<4096, 256, 0, stream>>>(qb_bf, freqs);
    rope_k_bf_kernel<<<256, 256, 0, stream>>>(kvpe, freqs, kpe_bf);
    rmsnorm_kernel<<<2048, 256, 0, stream>>>(kvpe, kv_lat_bf, kv_norm_w, 512, 640, 512);
    cast_bf16_kernel<<<2048, 256, 0, stream>>>(wkv_b, WA, 524288, 524288);
    // GEMM 4: kvb_bf = kv_lat_bf @ wkv_b^T + bkv_b
    gemm_mfma_kernel<__hip_bfloat16><<<dim3(32, 16), 256, 0, stream>>>(kv_lat_bf, 512, WA, 512, bkv_b, kvb_bf, 4096, 512);
    pack_vT_kernel<<<dim3(32, 16), 256, 0, stream>>>(kvb_bf, vT);
    // split-s attention: partials then combine (partial arena overwrites pool)
    attn_part_kernel<<<dim3(128, 16), 256, 0, stream>>>(qb_bf, kvb_bf, kpe_bf, vT, Opart, mlpart);
    attn_combine_kernel<<<dim3(32, 16), 256, 0, stream>>>(Opart, mlpart, yb_bf);
    cast_bf16_kernel<<<4096, 256, 0, stream>>>(wo, WA, 1048576, 1048576);
    // GEMM 5: out = yb_bf @ wo^T + bo  (f32 out)
    gemm_mfma_kernel<float><<<dim3(16, 16), 256, 0, stream>>>(yb_bf, 2048, WA, 2048, bo, out, 2048, 2048);
}

// Round 5
// 396.625 us; speedup vs baseline: 1.2728x; 1.1780x over previous
//
#include <hip/hip_runtime.h>
#include <hip/hip_bf16.h>

// MLA prefill: B=1, T=2048, C=2048, H=16, DN=128, DR=64, DV=128, QKD=192,
// RQ=1536, RKV=512. Inputs f32, output f32.
// Round 11:
//  * GEMM: 512-thread / 8-wave blocks (2 waves per SIMD hide the per-K-step
//    vmcnt drain inside one block -- grids here are 80-512 blocks, ~1/CU, so
//    co-residency can't help; intra-block wave ILP can). Same 128x128 tile,
//    BK=32, verified fragment/epilogue layouts. Wave = 32x64 quadrant.
//  * GEMM1+GEMM2 fused: one N=2176 dispatch (fused weight arena + bias),
//    per-block output split at colB>=1536 (12 vs 5 col-blocks, block-uniform).
//  * attn: round-2 monolithic restored (split-s reverted, was +10us); row-sum
//    l now computed by an extra mfma(P, ones) in the PV phase, deleting the
//    4-step shfl_xor sum chain per iteration.

#define T_DIM 2048
#define H_DIM 16
#define SCALE_F 0.07216878364870322f   // 192^-0.5
#define EPS_F 1e-6f
#define NEG_INF (-3.402823466e38f)

typedef __attribute__((ext_vector_type(8))) short short8;
typedef __attribute__((ext_vector_type(4))) float f32x4;
typedef __attribute__((address_space(3))) char lds_char;
typedef const __attribute__((address_space(1))) char glb_char;

__device__ inline void st_out(float* p, float v) { *p = v; }
__device__ inline void st_out(__hip_bfloat16* p, float v) { *p = __float2bfloat16(v); }

// ---------------- f32 -> bf16 cast (optionally zero-padded tail) ------------
__global__ void cast_bf16_kernel(const float* __restrict__ src,
                                 __hip_bfloat16* __restrict__ dst,
                                 int n4_src, int n4_dst) {
    int i = blockIdx.x * 256 + threadIdx.x;
    if (i >= n4_dst) return;
    float4 v = make_float4(0.f, 0.f, 0.f, 0.f);
    if (i < n4_src) v = ((const float4*)src)[i];
    dst[4 * i + 0] = __float2bfloat16(v.x);
    dst[4 * i + 1] = __float2bfloat16(v.y);
    dst[4 * i + 2] = __float2bfloat16(v.z);
    dst[4 * i + 3] = __float2bfloat16(v.w);
}

__global__ void pad_bias_kernel(const float* __restrict__ src, float* __restrict__ dst,
                                int n_src, int n_dst) {
    int i = blockIdx.x * 256 + threadIdx.x;
    if (i < n_dst) dst[i] = (i < n_src) ? src[i] : 0.f;
}

// ---------------- MFMA GEMM: C[M,N] = A[M,K] @ W[N,K]^T + bias[N] -----------
// 512 threads = 8 waves; wave w owns a 32x64 quadrant: wr=(w>>1)*32,
// wc=(w&1)*64, acc[2][4]. 2-phase LDS double-buffer (stage k+1 before
// compute k). Optional second output C2 (f32) for cols >= splitN
// (block-uniform: splitN multiple of 128). bias indexed by fused col.
template <typename OT>
__global__ __launch_bounds__(512) void gemm_mfma_kernel(
    const __hip_bfloat16* __restrict__ A, int lda,
    const __hip_bfloat16* __restrict__ W, int ldw,
    const float* __restrict__ bias,
    OT* __restrict__ C, int ldc,
    float* __restrict__ C2, int ldc2, int splitN, int K) {
    __shared__ __hip_bfloat16 As[2][128 * 32];
    __shared__ __hip_bfloat16 Bs[2][128 * 32];
    const int tid = threadIdx.x;
    const int w = tid >> 6, lane = tid & 63, qd = lane >> 4, lx = lane & 15;
    const int rowB = blockIdx.y * 128, colB = blockIdx.x * 128;
    const int wr = (w >> 1) * 32, wc = (w & 1) * 64;

    f32x4 acc[2][4];
#pragma unroll
    for (int i = 0; i < 2; ++i)
#pragma unroll
        for (int j = 0; j < 4; ++j) acc[i][j] = (f32x4)(0.f);

    auto stage = [&](int buf, int k0) {
        // 128x32 tile = 512 16B granules; one A + one B granule per thread
        const int g = tid, row = g >> 2, q = g & 3;
        const __hip_bfloat16* ga = A + (size_t)(rowB + row) * lda + k0 + q * 8;
        __builtin_amdgcn_global_load_lds((glb_char*)ga,
            (lds_char*)((char*)&As[buf][0] + (size_t)g * 16), 16, 0, 0);
        const __hip_bfloat16* gb = W + (size_t)(colB + row) * ldw + k0 + q * 8;
        __builtin_amdgcn_global_load_lds((glb_char*)gb,
            (lds_char*)((char*)&Bs[buf][0] + (size_t)g * 16), 16, 0, 0);
    };

    stage(0, 0);
    __syncthreads();          // buf0 ready
    int cur = 0;
    for (int k0 = 0; k0 < K; k0 += 32) {
        if (k0 + 32 < K) stage(cur ^ 1, k0 + 32);   // in flight across compute

        short8 a[2], b[4];
#pragma unroll
        for (int rt = 0; rt < 2; ++rt)
            a[rt] = *(const short8*)&As[cur][(wr + rt * 16 + lx) * 32 + qd * 8];
#pragma unroll
        for (int ct = 0; ct < 4; ++ct)
            b[ct] = *(const short8*)&Bs[cur][(wc + ct * 16 + lx) * 32 + qd * 8];
#pragma unroll
        for (int rt = 0; rt < 2; ++rt)
#pragma unroll
            for (int ct = 0; ct < 4; ++ct)
                acc[rt][ct] = __builtin_amdgcn_mfma_f32_16x16x32_bf16(a[rt], b[ct], acc[rt][ct], 0, 0, 0);
        __syncthreads();
        cur ^= 1;
    }

    // epilogue: C/D layout col=lane&15, row=4*qd+reg
    const bool second = (C2 != nullptr) && (colB >= splitN);
#pragma unroll
    for (int rt = 0; rt < 2; ++rt)
#pragma unroll
        for (int j = 0; j < 4; ++j) {
            const int row = rowB + wr + rt * 16 + 4 * qd + j;
#pragma unroll
            for (int ct = 0; ct < 4; ++ct) {
                const int col = colB + wc + ct * 16 + lx;
                const float v = acc[rt][ct][j] + bias[col];
                if (second) C2[(size_t)row * ldc2 + (col - splitN)] = v;
                else        st_out(&C[(size_t)row * ldc + col], v);
            }
        }
}

// ---------------- RMSNorm: f32 in -> bf16 out -------------------------------
__global__ void rmsnorm_kernel(const float* __restrict__ in, __hip_bfloat16* __restrict__ outp,
                               const float* __restrict__ w,
                               int D, int in_stride, int out_stride) {
    const int row = blockIdx.x;
    const float* p = in + (size_t)row * in_stride;
    __hip_bfloat16* o = outp + (size_t)row * out_stride;
    const int tid = threadIdx.x;  // 256
    float ss = 0.f;
    for (int i = tid; i < D; i += 256) { float v = p[i]; ss += v * v; }
    __shared__ float red[256];
    red[tid] = ss;
    __syncthreads();
    for (int off = 128; off > 0; off >>= 1) {
        if (tid < off) red[tid] += red[tid + off];
        __syncthreads();
    }
    const float scale = rsqrtf(red[0] / (float)D + EPS_F);
    for (int i = tid; i < D; i += 256)
        o[i] = __float2bfloat16(p[i] * scale * w[i]);
}

// ---------------- RoPE on q (in-place on bf16 qb: (T, H*192)) ---------------
__global__ void rope_q_bf_kernel(__hip_bfloat16* __restrict__ qb,
                                 const float* __restrict__ freqs) {
    const int idx = blockIdx.x * 256 + threadIdx.x;
    const int t = idx >> 9;
    const int h = (idx >> 5) & 15;
    const int i = idx & 31;
    const float f = freqs[t * 32 + i];
    const float c = cosf(f), s = sinf(f);
    __hip_bfloat16* p = qb + (size_t)t * 3072 + h * 192 + 128 + 2 * i;
    const float xr = __bfloat162float(p[0]), xi = __bfloat162float(p[1]);
    p[0] = __float2bfloat16(xr * c - xi * s);
    p[1] = __float2bfloat16(xr * s + xi * c);
}

// ---------------- RoPE on k_pe: kvpe f32 (T,640) cols[512:576) -> kpe bf16 --
__global__ void rope_k_bf_kernel(const float* __restrict__ kvpe,
                                 const float* __restrict__ freqs,
                                 __hip_bfloat16* __restrict__ kpe) {
    const int idx = blockIdx.x * 256 + threadIdx.x;  // 65536
    const int t = idx >> 5;
    const int i = idx & 31;
    const float f = freqs[t * 32 + i];
    const float c = cosf(f), s = sinf(f);
    const float* src = kvpe + (size_t)t * 640 + 512 + 2 * i;
    const float xr = src[0], xi = src[1];
    kpe[(size_t)t * 64 + 2 * i]     = __float2bfloat16(xr * c - xi * s);
    kpe[(size_t)t * 64 + 2 * i + 1] = __float2bfloat16(xr * s + xi * c);
}

// ---------------- pack V transposed: kvb_bf (T,H*256) -> vT (H,128,T) -------
__global__ void pack_vT_kernel(const __hip_bfloat16* __restrict__ kvb,
                               __hip_bfloat16* __restrict__ vT) {
    const int t0 = blockIdx.x * 64;
    const int h = blockIdx.y;
    const int tid = threadIdx.x;
    __shared__ __hip_bfloat16 Ls[64][136];
#pragma unroll
    for (int it = 0; it < 4; ++it) {
        int c = tid + 256 * it;
        int i = c >> 4, part = c & 15;
        *(uint4*)&Ls[i][part * 8] =
            *(const uint4*)(kvb + (size_t)(t0 + i) * 4096 + h * 256 + 128 + part * 8);
    }
    __syncthreads();
#pragma unroll
    for (int it = 0; it < 32; ++it) {
        int c = tid + 256 * it;
        int d = c >> 6, i = c & 63;
        vT[((size_t)(h * 128 + d)) * 2048 + t0 + i] = Ls[i][d];
    }
}

// ---------------- MFMA flash attention (y out in bf16) ----------------------
// Round-2 structure (LDS staging + named-reg prefetch + setprio). Row-sum l
// computed via mfma(P, ones) in PV instead of a 4-step shfl_xor chain.
__global__ __launch_bounds__(256) void attn_mfma_kernel(
    const __hip_bfloat16* __restrict__ q,
    const __hip_bfloat16* __restrict__ kv,
    const __hip_bfloat16* __restrict__ kpe,
    const __hip_bfloat16* __restrict__ vT,
    __hip_bfloat16* __restrict__ y) {
    const int qt = gridDim.x - 1 - blockIdx.x;   // longest blocks first
    const int h = blockIdx.y;
    const int q0 = qt * 64;
    const int tid = threadIdx.x;
    const int w = tid >> 6, lane = tid & 63, qd = lane >> 4, lx = lane & 15;

    __shared__ __hip_bfloat16 Ks[64][200];
    __shared__ __hip_bfloat16 Vs[128][72];
    __shared__ __hip_bfloat16 Ps[4][16][72];

    short8 qf[6];
    {
        const __hip_bfloat16* qrow =
            q + (size_t)(q0 + 16 * w + lx) * 3072 + h * 192 + qd * 8;
#pragma unroll
        for (int kc = 0; kc < 6; ++kc)
            qf[kc] = *(const short8*)(qrow + kc * 32);
    }

    f32x4 O[8];
#pragma unroll
    for (int i = 0; i < 8; ++i) O[i] = (f32x4)(0.f);
    float mrow[4], lrow[4];
#pragma unroll
    for (int j = 0; j < 4; ++j) { mrow[j] = NEG_INF; lrow[j] = 0.f; }

    const short8 vone = (short8)(short)0x3F80;   // bf16 1.0 splat

    // ---- prefetch state: 10 NAMED uint4 (40 VGPRs), never indexed ----
    uint4 k0r, k1r, k2r, k3r, pe0r, pe1r, v0r, v1r, v2r, v3r;
    const __hip_bfloat16* kvh = kv + h * 256;
    const __hip_bfloat16* vTh = vT + (size_t)h * 128 * 2048;

#define PREFETCH(S0)                                                               \
    do {                                                                           \
        const size_t kk_ = (size_t)(S0) + (tid >> 4);                              \
        const int kp_ = (tid & 15) * 8;                                            \
        k0r = *(const uint4*)(kvh + (kk_ +  0) * 4096 + kp_);                      \
        k1r = *(const uint4*)(kvh + (kk_ + 16) * 4096 + kp_);                      \
        k2r = *(const uint4*)(kvh + (kk_ + 32) * 4096 + kp_);                      \
        k3r = *(const uint4*)(kvh + (kk_ + 48) * 4096 + kp_);                      \
        const size_t pk_ = (size_t)(S0) + (tid >> 3);                              \
        const int pp_ = (tid & 7) * 8;                                             \
        pe0r = *(const uint4*)(kpe + (pk_ +  0) * 64 + pp_);                       \
        pe1r = *(const uint4*)(kpe + (pk_ + 32) * 64 + pp_);                       \
        const __hip_bfloat16* vp_ = vTh + ((size_t)(tid >> 3)) * 2048 + (S0) + pp_;\
        v0r = *(const uint4*)(vp_ + 0 * 65536);                                    \
        v1r = *(const uint4*)(vp_ + 1 * 65536);                                    \
        v2r = *(const uint4*)(vp_ + 2 * 65536);                                    \
        v3r = *(const uint4*)(vp_ + 3 * 65536);                                    \
    } while (0)

    PREFETCH(0);

    for (int s0 = 0; s0 <= q0 + 63; s0 += 64) {
        __syncthreads();   // all waves done reading LDS of previous tile
        // reg -> LDS (regs hold tile s0, prefetched last iteration/prologue)
        {
            const int kr_ = tid >> 4, kp_ = (tid & 15) * 8;
            *(uint4*)&Ks[kr_ +  0][kp_] = k0r;
            *(uint4*)&Ks[kr_ + 16][kp_] = k1r;
            *(uint4*)&Ks[kr_ + 32][kp_] = k2r;
            *(uint4*)&Ks[kr_ + 48][kp_] = k3r;
            const int pr_ = tid >> 3, pp_ = (tid & 7) * 8;
            *(uint4*)&Ks[pr_ +  0][128 + pp_] = pe0r;
            *(uint4*)&Ks[pr_ + 32][128 + pp_] = pe1r;
            *(uint4*)&Vs[pr_ +  0][pp_] = v0r;
            *(uint4*)&Vs[pr_ + 32][pp_] = v1r;
            *(uint4*)&Vs[pr_ + 64][pp_] = v2r;
            *(uint4*)&Vs[pr_ + 96][pp_] = v3r;
        }
        __syncthreads();   // tile visible to all waves

        // issue next tile's global loads NOW; latency hides under compute
        if (s0 + 64 <= q0) PREFETCH(s0 + 64);

        f32x4 S[4];
#pragma unroll
        for (int nt = 0; nt < 4; ++nt) S[nt] = (f32x4)(0.f);
        __builtin_amdgcn_s_setprio(1);
#pragma unroll
        for (int kc = 0; kc < 6; ++kc) {
            short8 a = qf[kc];
#pragma unroll
            for (int nt = 0; nt < 4; ++nt) {
                short8 b = *(const short8*)&Ks[nt * 16 + lx][kc * 32 + qd * 8];
                S[nt] = __builtin_amdgcn_mfma_f32_16x16x32_bf16(a, b, S[nt], 0, 0, 0);
            }
        }
        __builtin_amdgcn_s_setprio(0);

        float sv[4][4];
#pragma unroll
        for (int nt = 0; nt < 4; ++nt) {
            int col = s0 + nt * 16 + lx;
#pragma unroll
            for (int j = 0; j < 4; ++j) {
                int row = q0 + 16 * w + 4 * qd + j;
                float v = S[nt][j] * SCALE_F;
                sv[nt][j] = (col > row) ? NEG_INF : v;
            }
        }

        // ---- max-reduce (shfl) + exp + P write; sum comes from MFMA below --
        float mn[4], al[4];
#pragma unroll
        for (int j = 0; j < 4; ++j) {
            float rm = fmaxf(fmaxf(sv[0][j], sv[1][j]), fmaxf(sv[2][j], sv[3][j]));
#pragma unroll
            for (int msk = 1; msk < 16; msk <<= 1)
                rm = fmaxf(rm, __shfl_xor(rm, msk));
            mn[j] = fmaxf(mrow[j], rm);
            al[j] = __expf(mrow[j] - mn[j]);
            mrow[j] = mn[j];
        }
#pragma unroll
        for (int nt = 0; nt < 4; ++nt)
#pragma unroll
            for (int j = 0; j < 4; ++j) {
                float p = __expf(sv[nt][j] - mn[j]);
                Ps[w][4 * qd + j][nt * 16 + lx] = __float2bfloat16(p);
            }
#pragma unroll
        for (int nt = 0; nt < 8; ++nt)
#pragma unroll
            for (int j = 0; j < 4; ++j) O[nt][j] *= al[j];

        asm volatile("s_waitcnt lgkmcnt(0)" ::: "memory");

        // ---- PV + row-sum via mfma(P, ones) ----
        f32x4 lacc = (f32x4)(0.f);
        __builtin_amdgcn_s_setprio(1);
#pragma unroll
        for (int kc2 = 0; kc2 < 2; ++kc2) {
            short8 pa = *(const short8*)&Ps[w][lx][kc2 * 32 + qd * 8];
#pragma unroll
            for (int nt = 0; nt < 8; ++nt) {
                short8 vb = *(const short8*)&Vs[nt * 16 + lx][kc2 * 32 + qd * 8];
                O[nt] = __builtin_amdgcn_mfma_f32_16x16x32_bf16(pa, vb, O[nt], 0, 0, 0);
            }
            lacc = __builtin_amdgcn_mfma_f32_16x16x32_bf16(pa, vone, lacc, 0, 0, 0);
        }
        __builtin_amdgcn_s_setprio(0);

#pragma unroll
        for (int j = 0; j < 4; ++j)
            lrow[j] = lrow[j] * al[j] + lacc[j];
    }
#undef PREFETCH

#pragma unroll
    for (int j = 0; j < 4; ++j) {
        const float inv = 1.f / lrow[j];
        const int t = q0 + 16 * w + 4 * qd + j;
        __hip_bfloat16* yr = y + (size_t)t * 2048 + h * 128 + lx;
#pragma unroll
        for (int nt = 0; nt < 8; ++nt) yr[nt * 16] = __float2bfloat16(O[nt][j] * inv);
    }
}

extern "C" void kernel_launch(void* const* d_in, const int* in_sizes, int n_in,
                              void* d_out, int out_size, void* d_ws, size_t ws_size,
                              hipStream_t stream) {
    const float* x         = (const float*)d_in[0];
    const float* freqs     = (const float*)d_in[1];
    const float* wq_a      = (const float*)d_in[2];
    const float* bq_a      = (const float*)d_in[3];
    const float* q_norm_w  = (const float*)d_in[4];
    const float* wq_b      = (const float*)d_in[5];
    const float* bq_b      = (const float*)d_in[6];
    const float* wkv_a     = (const float*)d_in[7];
    const float* bkv_a     = (const float*)d_in[8];
    const float* kv_norm_w = (const float*)d_in[9];
    const float* wkv_b     = (const float*)d_in[10];
    const float* bkv_b     = (const float*)d_in[11];
    const float* wo        = (const float*)d_in[12];
    const float* bo        = (const float*)d_in[13];
    float* out = (float*)d_out;

    // Workspace layout (~74 MB).
    char* p = (char*)d_ws;
    float* q_lat = (float*)p;                        p += (size_t)2048 * 1536 * 4;  // later hosts yb_bf
    float* kvpe  = (float*)p;                        p += (size_t)2048 * 640 * 4;
    __hip_bfloat16* x_bf      = (__hip_bfloat16*)p;  p += (size_t)2048 * 2048 * 2;  // later hosts vT
    __hip_bfloat16* q_lat_bf  = (__hip_bfloat16*)p;  p += (size_t)2048 * 1536 * 2;
    __hip_bfloat16* qb_bf     = (__hip_bfloat16*)p;  p += (size_t)2048 * 3072 * 2;
    __hip_bfloat16* kv_lat_bf = (__hip_bfloat16*)p;  p += (size_t)2048 * 512 * 2;
    __hip_bfloat16* kvb_bf    = (__hip_bfloat16*)p;  p += (size_t)2048 * 4096 * 2;
    __hip_bfloat16* kpe_bf    = (__hip_bfloat16*)p;  p += (size_t)2048 * 64 * 2;
    __hip_bfloat16* WA        = (__hip_bfloat16*)p;  p += (size_t)3072 * 1536 * 2;  // weight arena (9.44 MB)
    float* bias_ab = (float*)p;                      p += (size_t)2176 * 4;         // fused bq_a ++ bkv_a(pad)
    __hip_bfloat16* vT    = x_bf;                    // alias: x_bf dead after fused GEMM
    __hip_bfloat16* yb_bf = (__hip_bfloat16*)q_lat;  // alias: q_lat dead after rmsnorm

    // ---- casts & pads ----
    cast_bf16_kernel<<<4096, 256, 0, stream>>>(x, x_bf, 1048576, 1048576);
    // fused weight arena: rows 0..1535 = wq_a, rows 1536..2175 = wkv_a (padded)
    cast_bf16_kernel<<<3072, 256, 0, stream>>>(wq_a, WA, 786432, 786432);
    cast_bf16_kernel<<<1280, 256, 0, stream>>>(wkv_a, WA + (size_t)1536 * 2048, 294912, 327680);
    pad_bias_kernel<<<6, 256, 0, stream>>>(bq_a, bias_ab, 1536, 1536);
    pad_bias_kernel<<<3, 256, 0, stream>>>(bkv_a, bias_ab + 1536, 576, 640);
    // GEMM 1+2 fused: [q_lat | kvpe] = x @ [wq_a; wkv_a]^T + bias  (f32 out)
    gemm_mfma_kernel<float><<<dim3(17, 16), 512, 0, stream>>>(
        x_bf, 2048, WA, 2048, bias_ab, q_lat, 1536, kvpe, 640, 1536, 2048);
    // rmsnorm q -> bf16
    rmsnorm_kernel<<<2048, 256, 0, stream>>>(q_lat, q_lat_bf, q_norm_w, 1536, 1536, 1536);
    cast_bf16_kernel<<<4608, 256, 0, stream>>>(wq_b, WA, 1179648, 1179648);
    // GEMM 3: qb_bf = q_lat_bf @ wq_b^T + bq_b
    gemm_mfma_kernel<__hip_bfloat16><<<dim3(24, 16), 512, 0, stream>>>(
        q_lat_bf, 1536, WA, 1536, bq_b, qb_bf, 3072, nullptr, 0, 1 << 30, 1536);
    rope_q_bf_kernel<<<4096, 256, 0, stream>>>(qb_bf, freqs);
    rope_k_bf_kernel<<<256, 256, 0, stream>>>(kvpe, freqs, kpe_bf);
    rmsnorm_kernel<<<2048, 256, 0, stream>>>(kvpe, kv_lat_bf, kv_norm_w, 512, 640, 512);
    cast_bf16_kernel<<<2048, 256, 0, stream>>>(wkv_b, WA, 524288, 524288);
    // GEMM 4: kvb_bf = kv_lat_bf @ wkv_b^T + bkv_b
    gemm_mfma_kernel<__hip_bfloat16><<<dim3(32, 16), 512, 0, stream>>>(
        kv_lat_bf, 512, WA, 512, bkv_b, kvb_bf, 4096, nullptr, 0, 1 << 30, 512);
    pack_vT_kernel<<<dim3(32, 16), 256, 0, stream>>>(kvb_bf, vT);
    attn_mfma_kernel<<<dim3(32, 16), 256, 0, stream>>>(qb_bf, kvb_bf, kpe_bf, vT, yb_bf);
    cast_bf16_kernel<<<4096, 256, 0, stream>>>(wo, WA, 1048576, 1048576);
    // GEMM 5: out = yb_bf @ wo^T + bo  (f32 out)
    gemm_mfma_kernel<float><<<dim3(16, 16), 512, 0, stream>>>(
        yb_bf, 2048, WA, 2048, bo, out, 2048, nullptr, 0, 1 << 30, 2048);
}

// Round 6
// 346.079 us; speedup vs baseline: 1.4587x; 1.1461x over previous
//
#include <hip/hip_runtime.h>
#include <hip/hip_bf16.h>

// MLA prefill: B=1, T=2048, C=2048, H=16, DN=128, DR=64, DV=128, QKD=192,
// RQ=1536, RKV=512. Inputs f32, output f32.
// Round 12:
//  * attn: XOR-16B-slot swizzle on Ks/Vs (was 8-way bank conflict on every
//    QK/PV ds_read_b128); T13 defer-max (skip shfl-max + O-rescale when
//    wave-uniform max growth <= 8); XCD-chunked decode (2 heads per XCD).
//  * GEMM: BK=64 (half the barrier drains), source-preswizzled
//    global_load_lds + swizzled ds_read (16-way conflict at BK=64 otherwise),
//    bijective XCD remap. 512 thr / 8 waves kept from round 11.
//  * Launch fusion: one weight-cast for wq_a+wkv_a, one bias-pad kernel,
//    rmsnorm_kv + rope_k fused.

#define T_DIM 2048
#define H_DIM 16
#define SCALE_F 0.07216878364870322f   // 192^-0.5
#define EPS_F 1e-6f
#define NEG_INF (-3.402823466e38f)

typedef __attribute__((ext_vector_type(8))) short short8;
typedef __attribute__((ext_vector_type(4))) float f32x4;
typedef __attribute__((address_space(3))) char lds_char;
typedef const __attribute__((address_space(1))) char glb_char;

__device__ inline void st_out(float* p, float v) { *p = v; }
__device__ inline void st_out(__hip_bfloat16* p, float v) { *p = __float2bfloat16(v); }

// ---------------- f32 -> bf16 cast (optionally zero-padded tail) ------------
__global__ void cast_bf16_kernel(const float* __restrict__ src,
                                 __hip_bfloat16* __restrict__ dst,
                                 int n4_src, int n4_dst) {
    int i = blockIdx.x * 256 + threadIdx.x;
    if (i >= n4_dst) return;
    float4 v = make_float4(0.f, 0.f, 0.f, 0.f);
    if (i < n4_src) v = ((const float4*)src)[i];
    dst[4 * i + 0] = __float2bfloat16(v.x);
    dst[4 * i + 1] = __float2bfloat16(v.y);
    dst[4 * i + 2] = __float2bfloat16(v.z);
    dst[4 * i + 3] = __float2bfloat16(v.w);
}

// fused cast of wq_a (1536x2048) and wkv_a (576x2048, padded to 640 rows)
// into the WA arena: rows 0..1535 = wq_a, rows 1536..2175 = wkv_a/0.
__global__ void cast_wa_kernel(const float* __restrict__ wq_a,
                               const float* __restrict__ wkv_a,
                               __hip_bfloat16* __restrict__ WA) {
    int i = blockIdx.x * 256 + threadIdx.x;          // granule of 4 elems
    if (i >= 1114112) return;                        // 786432 + 327680
    float4 v = make_float4(0.f, 0.f, 0.f, 0.f);
    if (i < 786432) v = ((const float4*)wq_a)[i];
    else if (i - 786432 < 294912) v = ((const float4*)wkv_a)[i - 786432];
    __hip_bfloat16* dst = WA + 4 * (size_t)i;
    dst[0] = __float2bfloat16(v.x);
    dst[1] = __float2bfloat16(v.y);
    dst[2] = __float2bfloat16(v.z);
    dst[3] = __float2bfloat16(v.w);
}

// fused bias: [bq_a(1536) | bkv_a(576) | 0(64)] -> 2176 floats
__global__ void bias_ab_kernel(const float* __restrict__ bq_a,
                               const float* __restrict__ bkv_a,
                               float* __restrict__ dst) {
    int i = blockIdx.x * 256 + threadIdx.x;
    if (i >= 2176) return;
    dst[i] = (i < 1536) ? bq_a[i] : ((i - 1536) < 576 ? bkv_a[i - 1536] : 0.f);
}

// ---------------- MFMA GEMM: C[M,N] = A[M,K] @ W[N,K]^T + bias[N] -----------
// 512 threads = 8 waves; wave w owns a 32x64 quadrant. BK=64, 2-phase LDS
// double-buffer. LDS rows are 128 B with XOR-16B-slot swizzle: slot' =
// slot ^ (row&7); global_load_lds keeps a LINEAR dest and pre-swizzles the
// SOURCE column (rule #21); ds_read applies the same XOR. Bijective XCD remap.
template <typename OT>
__global__ __launch_bounds__(512) void gemm_mfma_kernel(
    const __hip_bfloat16* __restrict__ A, int lda,
    const __hip_bfloat16* __restrict__ W, int ldw,
    const float* __restrict__ bias,
    OT* __restrict__ C, int ldc,
    float* __restrict__ C2, int ldc2, int splitN, int K) {
    __shared__ __hip_bfloat16 As[2][128 * 64];
    __shared__ __hip_bfloat16 Bs[2][128 * 64];
    const int tid = threadIdx.x;
    const int w = tid >> 6, lane = tid & 63, qd = lane >> 4, lx = lane & 15;

    // bijective XCD remap (m204): contiguous chunk of tiles per XCD
    const int nwg = gridDim.x * gridDim.y;
    const int o = blockIdx.y * gridDim.x + blockIdx.x;
    const int qx = nwg >> 3, rx = nwg & 7;
    const int xcd = o & 7, idx = o >> 3;
    const int neu = (xcd < rx ? xcd * (qx + 1) : rx * (qx + 1) + (xcd - rx) * qx) + idx;
    const int rowB = (neu / gridDim.x) * 128, colB = (neu % gridDim.x) * 128;

    const int wr = (w >> 1) * 32, wc = (w & 1) * 64;

    f32x4 acc[2][4];
#pragma unroll
    for (int i = 0; i < 2; ++i)
#pragma unroll
        for (int j = 0; j < 4; ++j) acc[i][j] = (f32x4)(0.f);

    auto stage = [&](int buf, int k0) {
#pragma unroll
        for (int it = 0; it < 2; ++it) {
            const int g = tid + it * 512;              // 0..1023 granules
            const int row = g >> 3, s = g & 7;
            const int sc = (s ^ (row & 7)) * 8;        // pre-swizzled src col
            const __hip_bfloat16* ga = A + (size_t)(rowB + row) * lda + k0 + sc;
            __builtin_amdgcn_global_load_lds((glb_char*)ga,
                (lds_char*)((char*)&As[buf][0] + (size_t)g * 16), 16, 0, 0);
            const __hip_bfloat16* gb = W + (size_t)(colB + row) * ldw + k0 + sc;
            __builtin_amdgcn_global_load_lds((glb_char*)gb,
                (lds_char*)((char*)&Bs[buf][0] + (size_t)g * 16), 16, 0, 0);
        }
    };

    stage(0, 0);
    __syncthreads();          // buf0 ready
    int cur = 0;
    const int swz = (lx & 7) << 4;    // row&7 == lx&7 for all fragment rows
    for (int k0 = 0; k0 < K; k0 += 64) {
        if (k0 + 64 < K) stage(cur ^ 1, k0 + 64);   // in flight across compute

#pragma unroll
        for (int kk = 0; kk < 2; ++kk) {
            short8 a[2], b[4];
#pragma unroll
            for (int rt = 0; rt < 2; ++rt)
                a[rt] = *(const short8*)((char*)&As[cur][0]
                    + (size_t)(wr + rt * 16 + lx) * 128 + ((kk * 64 + qd * 16) ^ swz));
#pragma unroll
            for (int ct = 0; ct < 4; ++ct)
                b[ct] = *(const short8*)((char*)&Bs[cur][0]
                    + (size_t)(wc + ct * 16 + lx) * 128 + ((kk * 64 + qd * 16) ^ swz));
#pragma unroll
            for (int rt = 0; rt < 2; ++rt)
#pragma unroll
                for (int ct = 0; ct < 4; ++ct)
                    acc[rt][ct] = __builtin_amdgcn_mfma_f32_16x16x32_bf16(a[rt], b[ct], acc[rt][ct], 0, 0, 0);
        }
        __syncthreads();
        cur ^= 1;
    }

    // epilogue: C/D layout col=lane&15, row=4*qd+reg
    const bool second = (C2 != nullptr) && (colB >= splitN);
#pragma unroll
    for (int rt = 0; rt < 2; ++rt)
#pragma unroll
        for (int j = 0; j < 4; ++j) {
            const int row = rowB + wr + rt * 16 + 4 * qd + j;
#pragma unroll
            for (int ct = 0; ct < 4; ++ct) {
                const int col = colB + wc + ct * 16 + lx;
                const float v = acc[rt][ct][j] + bias[col];
                if (second) C2[(size_t)row * ldc2 + (col - splitN)] = v;
                else        st_out(&C[(size_t)row * ldc + col], v);
            }
        }
}

// ---------------- RMSNorm: f32 in -> bf16 out -------------------------------
__global__ void rmsnorm_kernel(const float* __restrict__ in, __hip_bfloat16* __restrict__ outp,
                               const float* __restrict__ w,
                               int D, int in_stride, int out_stride) {
    const int row = blockIdx.x;
    const float* p = in + (size_t)row * in_stride;
    __hip_bfloat16* o = outp + (size_t)row * out_stride;
    const int tid = threadIdx.x;  // 256
    float ss = 0.f;
    for (int i = tid; i < D; i += 256) { float v = p[i]; ss += v * v; }
    __shared__ float red[256];
    red[tid] = ss;
    __syncthreads();
    for (int off = 128; off > 0; off >>= 1) {
        if (tid < off) red[tid] += red[tid + off];
        __syncthreads();
    }
    const float scale = rsqrtf(red[0] / (float)D + EPS_F);
    for (int i = tid; i < D; i += 256)
        o[i] = __float2bfloat16(p[i] * scale * w[i]);
}

// ---------------- fused rmsnorm(kv_lat) + rope(k_pe) per row ----------------
// kvpe f32 (T,640): cols 0..511 rmsnorm -> kv_lat_bf; cols 512..575 rope -> kpe.
__global__ void rmsnorm_rope_kv_kernel(const float* __restrict__ kvpe,
                                       __hip_bfloat16* __restrict__ kv_lat_bf,
                                       const float* __restrict__ w,
                                       const float* __restrict__ freqs,
                                       __hip_bfloat16* __restrict__ kpe) {
    const int row = blockIdx.x;
    const float* p = kvpe + (size_t)row * 640;
    const int tid = threadIdx.x;  // 256
    float v0 = p[tid], v1 = p[tid + 256];
    __shared__ float red[256];
    red[tid] = v0 * v0 + v1 * v1;
    __syncthreads();
    for (int off = 128; off > 0; off >>= 1) {
        if (tid < off) red[tid] += red[tid + off];
        __syncthreads();
    }
    const float scale = rsqrtf(red[0] / 512.f + EPS_F);
    __hip_bfloat16* o = kv_lat_bf + (size_t)row * 512;
    o[tid]       = __float2bfloat16(v0 * scale * w[tid]);
    o[tid + 256] = __float2bfloat16(v1 * scale * w[tid + 256]);
    if (tid < 32) {
        const float f = freqs[row * 32 + tid];
        const float c = cosf(f), s = sinf(f);
        const float xr = p[512 + 2 * tid], xi = p[512 + 2 * tid + 1];
        kpe[(size_t)row * 64 + 2 * tid]     = __float2bfloat16(xr * c - xi * s);
        kpe[(size_t)row * 64 + 2 * tid + 1] = __float2bfloat16(xr * s + xi * c);
    }
}

// ---------------- RoPE on q (in-place on bf16 qb: (T, H*192)) ---------------
__global__ void rope_q_bf_kernel(__hip_bfloat16* __restrict__ qb,
                                 const float* __restrict__ freqs) {
    const int idx = blockIdx.x * 256 + threadIdx.x;
    const int t = idx >> 9;
    const int h = (idx >> 5) & 15;
    const int i = idx & 31;
    const float f = freqs[t * 32 + i];
    const float c = cosf(f), s = sinf(f);
    __hip_bfloat16* p = qb + (size_t)t * 3072 + h * 192 + 128 + 2 * i;
    const float xr = __bfloat162float(p[0]), xi = __bfloat162float(p[1]);
    p[0] = __float2bfloat16(xr * c - xi * s);
    p[1] = __float2bfloat16(xr * s + xi * c);
}

// ---------------- pack V transposed: kvb_bf (T,H*256) -> vT (H,128,T) -------
__global__ void pack_vT_kernel(const __hip_bfloat16* __restrict__ kvb,
                               __hip_bfloat16* __restrict__ vT) {
    const int t0 = blockIdx.x * 64;
    const int h = blockIdx.y;
    const int tid = threadIdx.x;
    __shared__ __hip_bfloat16 Ls[64][136];
#pragma unroll
    for (int it = 0; it < 4; ++it) {
        int c = tid + 256 * it;
        int i = c >> 4, part = c & 15;
        *(uint4*)&Ls[i][part * 8] =
            *(const uint4*)(kvb + (size_t)(t0 + i) * 4096 + h * 256 + 128 + part * 8);
    }
    __syncthreads();
#pragma unroll
    for (int it = 0; it < 32; ++it) {
        int c = tid + 256 * it;
        int d = c >> 6, i = c & 63;
        vT[((size_t)(h * 128 + d)) * 2048 + t0 + i] = Ls[i][d];
    }
}

// ---------------- MFMA flash attention (y out in bf16) ----------------------
// K/V LDS rows are 128B-stripe XOR-swizzled: byte ^= ((row&7)<<4) on both the
// ds_write and ds_read side (reg-staged, so direct swizzle is legal).
// T13 defer-max: wave-uniform skip of shfl-max + O-rescale when per-lane max
// growth <= 8. Row-sum via mfma(P, ones). XCD-chunked decode: 2 heads/XCD.
__global__ __launch_bounds__(256) void attn_mfma_kernel(
    const __hip_bfloat16* __restrict__ q,
    const __hip_bfloat16* __restrict__ kv,
    const __hip_bfloat16* __restrict__ kpe,
    const __hip_bfloat16* __restrict__ vT,
    __hip_bfloat16* __restrict__ y) {
    const int o = blockIdx.x;             // 512 = 8 XCD * 64
    const int xcd = o & 7, slot = o >> 3;
    const int h  = xcd * 2 + (slot & 1);  // each XCD owns 2 heads (KV in its L2)
    const int qt = 31 - (slot >> 1);      // longest blocks first
    const int q0 = qt * 64;
    const int tid = threadIdx.x;
    const int w = tid >> 6, lane = tid & 63, qd = lane >> 4, lx = lane & 15;

    __shared__ __hip_bfloat16 KsB[64 * 192];   // 384 B rows: K[0:256) pe[256:384)
    __shared__ __hip_bfloat16 VsB[128 * 64];   // 128 B rows
    __shared__ __hip_bfloat16 Ps[4][16][72];

#define KS_ADDR(row, boff) ((char*)KsB + (size_t)(row) * 384 + ((boff) ^ (((row) & 7) << 4)))
#define VS_ADDR(row, boff) ((char*)VsB + (size_t)(row) * 128 + ((boff) ^ (((row) & 7) << 4)))

    short8 qf[6];
    {
        const __hip_bfloat16* qrow =
            q + (size_t)(q0 + 16 * w + lx) * 3072 + h * 192 + qd * 8;
#pragma unroll
        for (int kc = 0; kc < 6; ++kc)
            qf[kc] = *(const short8*)(qrow + kc * 32);
    }

    f32x4 O[8];
#pragma unroll
    for (int i = 0; i < 8; ++i) O[i] = (f32x4)(0.f);
    float mrow[4], lrow[4];
#pragma unroll
    for (int j = 0; j < 4; ++j) { mrow[j] = NEG_INF; lrow[j] = 0.f; }

    const short8 vone = (short8)(short)0x3F80;   // bf16 1.0 splat

    // ---- prefetch state: 10 NAMED uint4 (40 VGPRs), never indexed ----
    uint4 k0r, k1r, k2r, k3r, pe0r, pe1r, v0r, v1r, v2r, v3r;
    const __hip_bfloat16* kvh = kv + h * 256;
    const __hip_bfloat16* vTh = vT + (size_t)h * 128 * 2048;

#define PREFETCH(S0)                                                               \
    do {                                                                           \
        const size_t kk_ = (size_t)(S0) + (tid >> 4);                              \
        const int kp_ = (tid & 15) * 8;                                            \
        k0r = *(const uint4*)(kvh + (kk_ +  0) * 4096 + kp_);                      \
        k1r = *(const uint4*)(kvh + (kk_ + 16) * 4096 + kp_);                      \
        k2r = *(const uint4*)(kvh + (kk_ + 32) * 4096 + kp_);                      \
        k3r = *(const uint4*)(kvh + (kk_ + 48) * 4096 + kp_);                      \
        const size_t pk_ = (size_t)(S0) + (tid >> 3);                              \
        const int pp_ = (tid & 7) * 8;                                             \
        pe0r = *(const uint4*)(kpe + (pk_ +  0) * 64 + pp_);                       \
        pe1r = *(const uint4*)(kpe + (pk_ + 32) * 64 + pp_);                       \
        const __hip_bfloat16* vp_ = vTh + ((size_t)(tid >> 3)) * 2048 + (S0) + pp_;\
        v0r = *(const uint4*)(vp_ + 0 * 65536);                                    \
        v1r = *(const uint4*)(vp_ + 1 * 65536);                                    \
        v2r = *(const uint4*)(vp_ + 2 * 65536);                                    \
        v3r = *(const uint4*)(vp_ + 3 * 65536);                                    \
    } while (0)

    PREFETCH(0);

    for (int s0 = 0; s0 <= q0 + 63; s0 += 64) {
        __syncthreads();   // all waves done reading LDS of previous tile
        // reg -> LDS, swizzled dest (regs hold tile s0)
        {
            const int kr_ = tid >> 4, kb_ = (tid & 15) * 16;
            *(uint4*)KS_ADDR(kr_ +  0, kb_) = k0r;
            *(uint4*)KS_ADDR(kr_ + 16, kb_) = k1r;
            *(uint4*)KS_ADDR(kr_ + 32, kb_) = k2r;
            *(uint4*)KS_ADDR(kr_ + 48, kb_) = k3r;
            const int pr_ = tid >> 3, pb_ = (tid & 7) * 16;
            *(uint4*)KS_ADDR(pr_ +  0, 256 + pb_) = pe0r;
            *(uint4*)KS_ADDR(pr_ + 32, 256 + pb_) = pe1r;
            *(uint4*)VS_ADDR(pr_ +  0, pb_) = v0r;
            *(uint4*)VS_ADDR(pr_ + 32, pb_) = v1r;
            *(uint4*)VS_ADDR(pr_ + 64, pb_) = v2r;
            *(uint4*)VS_ADDR(pr_ + 96, pb_) = v3r;
        }
        __syncthreads();   // tile visible to all waves

        // issue next tile's global loads NOW; latency hides under compute
        if (s0 + 64 <= q0) PREFETCH(s0 + 64);

        f32x4 S[4];
#pragma unroll
        for (int nt = 0; nt < 4; ++nt) S[nt] = (f32x4)(0.f);
        __builtin_amdgcn_s_setprio(1);
#pragma unroll
        for (int kc = 0; kc < 6; ++kc) {
            short8 a = qf[kc];
#pragma unroll
            for (int nt = 0; nt < 4; ++nt) {
                short8 b = *(const short8*)KS_ADDR(nt * 16 + lx, kc * 64 + qd * 16);
                S[nt] = __builtin_amdgcn_mfma_f32_16x16x32_bf16(a, b, S[nt], 0, 0, 0);
            }
        }
        __builtin_amdgcn_s_setprio(0);

        float sv[4][4];
#pragma unroll
        for (int nt = 0; nt < 4; ++nt) {
            int col = s0 + nt * 16 + lx;
#pragma unroll
            for (int j = 0; j < 4; ++j) {
                int row = q0 + 16 * w + 4 * qd + j;
                float v = S[nt][j] * SCALE_F;
                sv[nt][j] = (col > row) ? NEG_INF : v;
            }
        }

        // ---- T13 defer-max: full path only when max grew beyond threshold --
        float pmax[4];
#pragma unroll
        for (int j = 0; j < 4; ++j)
            pmax[j] = fmaxf(fmaxf(sv[0][j], sv[1][j]), fmaxf(sv[2][j], sv[3][j]));
        const bool need = !__all((pmax[0] <= mrow[0] + 8.f) &&
                                 (pmax[1] <= mrow[1] + 8.f) &&
                                 (pmax[2] <= mrow[2] + 8.f) &&
                                 (pmax[3] <= mrow[3] + 8.f));
        if (need) {
            float al[4];
#pragma unroll
            for (int j = 0; j < 4; ++j) {
                float rm = pmax[j];
#pragma unroll
                for (int msk = 1; msk < 16; msk <<= 1)
                    rm = fmaxf(rm, __shfl_xor(rm, msk));
                const float mn = fmaxf(mrow[j], rm);
                al[j] = __expf(mrow[j] - mn);
                mrow[j] = mn;
                lrow[j] *= al[j];
            }
#pragma unroll
            for (int nt = 0; nt < 8; ++nt)
#pragma unroll
                for (int j = 0; j < 4; ++j) O[nt][j] *= al[j];
        }
#pragma unroll
        for (int nt = 0; nt < 4; ++nt)
#pragma unroll
            for (int j = 0; j < 4; ++j) {
                float p = __expf(sv[nt][j] - mrow[j]);
                Ps[w][4 * qd + j][nt * 16 + lx] = __float2bfloat16(p);
            }

        asm volatile("s_waitcnt lgkmcnt(0)" ::: "memory");

        // ---- PV + row-sum via mfma(P, ones) ----
        f32x4 lacc = (f32x4)(0.f);
        __builtin_amdgcn_s_setprio(1);
#pragma unroll
        for (int kc2 = 0; kc2 < 2; ++kc2) {
            short8 pa = *(const short8*)&Ps[w][lx][kc2 * 32 + qd * 8];
#pragma unroll
            for (int nt = 0; nt < 8; ++nt) {
                short8 vb = *(const short8*)VS_ADDR(nt * 16 + lx, kc2 * 64 + qd * 16);
                O[nt] = __builtin_amdgcn_mfma_f32_16x16x32_bf16(pa, vb, O[nt], 0, 0, 0);
            }
            lacc = __builtin_amdgcn_mfma_f32_16x16x32_bf16(pa, vone, lacc, 0, 0, 0);
        }
        __builtin_amdgcn_s_setprio(0);

#pragma unroll
        for (int j = 0; j < 4; ++j) lrow[j] += lacc[j];
    }
#undef PREFETCH
#undef KS_ADDR
#undef VS_ADDR

#pragma unroll
    for (int j = 0; j < 4; ++j) {
        const float inv = 1.f / lrow[j];
        const int t = q0 + 16 * w + 4 * qd + j;
        __hip_bfloat16* yr = y + (size_t)t * 2048 + h * 128 + lx;
#pragma unroll
        for (int nt = 0; nt < 8; ++nt) yr[nt * 16] = __float2bfloat16(O[nt][j] * inv);
    }
}

extern "C" void kernel_launch(void* const* d_in, const int* in_sizes, int n_in,
                              void* d_out, int out_size, void* d_ws, size_t ws_size,
                              hipStream_t stream) {
    const float* x         = (const float*)d_in[0];
    const float* freqs     = (const float*)d_in[1];
    const float* wq_a      = (const float*)d_in[2];
    const float* bq_a      = (const float*)d_in[3];
    const float* q_norm_w  = (const float*)d_in[4];
    const float* wq_b      = (const float*)d_in[5];
    const float* bq_b      = (const float*)d_in[6];
    const float* wkv_a     = (const float*)d_in[7];
    const float* bkv_a     = (const float*)d_in[8];
    const float* kv_norm_w = (const float*)d_in[9];
    const float* wkv_b     = (const float*)d_in[10];
    const float* bkv_b     = (const float*)d_in[11];
    const float* wo        = (const float*)d_in[12];
    const float* bo        = (const float*)d_in[13];
    float* out = (float*)d_out;

    // Workspace layout (~74 MB).
    char* p = (char*)d_ws;
    float* q_lat = (float*)p;                        p += (size_t)2048 * 1536 * 4;  // later hosts yb_bf
    float* kvpe  = (float*)p;                        p += (size_t)2048 * 640 * 4;
    __hip_bfloat16* x_bf      = (__hip_bfloat16*)p;  p += (size_t)2048 * 2048 * 2;  // later hosts vT
    __hip_bfloat16* q_lat_bf  = (__hip_bfloat16*)p;  p += (size_t)2048 * 1536 * 2;
    __hip_bfloat16* qb_bf     = (__hip_bfloat16*)p;  p += (size_t)2048 * 3072 * 2;
    __hip_bfloat16* kv_lat_bf = (__hip_bfloat16*)p;  p += (size_t)2048 * 512 * 2;
    __hip_bfloat16* kvb_bf    = (__hip_bfloat16*)p;  p += (size_t)2048 * 4096 * 2;
    __hip_bfloat16* kpe_bf    = (__hip_bfloat16*)p;  p += (size_t)2048 * 64 * 2;
    __hip_bfloat16* WA        = (__hip_bfloat16*)p;  p += (size_t)3072 * 1536 * 2;  // weight arena (9.44 MB)
    float* bias_ab = (float*)p;                      p += (size_t)2176 * 4;         // fused bq_a ++ bkv_a(pad)
    __hip_bfloat16* vT    = x_bf;                    // alias: x_bf dead after fused GEMM
    __hip_bfloat16* yb_bf = (__hip_bfloat16*)q_lat;  // alias: q_lat dead after rmsnorm

    // ---- casts & pads ----
    cast_bf16_kernel<<<4096, 256, 0, stream>>>(x, x_bf, 1048576, 1048576);
    cast_wa_kernel<<<4352, 256, 0, stream>>>(wq_a, wkv_a, WA);
    bias_ab_kernel<<<9, 256, 0, stream>>>(bq_a, bkv_a, bias_ab);
    // GEMM 1+2 fused: [q_lat | kvpe] = x @ [wq_a; wkv_a]^T + bias  (f32 out)
    gemm_mfma_kernel<float><<<dim3(17, 16), 512, 0, stream>>>(
        x_bf, 2048, WA, 2048, bias_ab, q_lat, 1536, kvpe, 640, 1536, 2048);
    // rmsnorm q -> bf16
    rmsnorm_kernel<<<2048, 256, 0, stream>>>(q_lat, q_lat_bf, q_norm_w, 1536, 1536, 1536);
    cast_bf16_kernel<<<4608, 256, 0, stream>>>(wq_b, WA, 1179648, 1179648);
    // GEMM 3: qb_bf = q_lat_bf @ wq_b^T + bq_b
    gemm_mfma_kernel<__hip_bfloat16><<<dim3(24, 16), 512, 0, stream>>>(
        q_lat_bf, 1536, WA, 1536, bq_b, qb_bf, 3072, nullptr, 0, 1 << 30, 1536);
    rope_q_bf_kernel<<<4096, 256, 0, stream>>>(qb_bf, freqs);
    rmsnorm_rope_kv_kernel<<<2048, 256, 0, stream>>>(kvpe, kv_lat_bf, kv_norm_w, freqs, kpe_bf);
    cast_bf16_kernel<<<2048, 256, 0, stream>>>(wkv_b, WA, 524288, 524288);
    // GEMM 4: kvb_bf = kv_lat_bf @ wkv_b^T + bkv_b
    gemm_mfma_kernel<__hip_bfloat16><<<dim3(32, 16), 512, 0, stream>>>(
        kv_lat_bf, 512, WA, 512, bkv_b, kvb_bf, 4096, nullptr, 0, 1 << 30, 512);
    pack_vT_kernel<<<dim3(32, 16), 256, 0, stream>>>(kvb_bf, vT);
    attn_mfma_kernel<<<512, 256, 0, stream>>>(qb_bf, kvb_bf, kpe_bf, vT, yb_bf);
    cast_bf16_kernel<<<4096, 256, 0, stream>>>(wo, WA, 1048576, 1048576);
    // GEMM 5: out = yb_bf @ wo^T + bo  (f32 out)
    gemm_mfma_kernel<float><<<dim3(16, 16), 512, 0, stream>>>(
        yb_bf, 2048, WA, 2048, bo, out, 2048, nullptr, 0, 1 << 30, 2048);
}